// Round 1
// baseline (10201.237 us; speedup 1.0000x reference)
//
#include <hip/hip_runtime.h>
#include <cstddef>
#include <cstdint>

// Problem constants (match reference)
constexpr int CB  = 2;     // batch
constexpr int CS  = 2048;  // seq len
constexpr int CDM = 1024;  // d_model
constexpr int CH  = 16;    // heads
constexpr int CHD = 64;    // head dim
constexpr int CTPF = 128;  // tokens per frame
constexpr int CNF = 16;    // frames

// ---------------------------------------------------------------------------
// GEMM: C[M,N] = A[M,K] @ B[N,K]^T + bias[N]
// 128x128 tile, BK=16, 256 threads, 8x8 micro-tile, LDS stored [k][row].
// ---------------------------------------------------------------------------
__global__ __launch_bounds__(256) void gemm_bt_bias(
    const float* __restrict__ A, const float* __restrict__ Bm,
    const float* __restrict__ bias, float* __restrict__ C,
    int M, int N, int K) {
  __shared__ float As[16][128];
  __shared__ float Bs[16][128];
  const int tid = threadIdx.x;
  const int bm = blockIdx.y * 128;
  const int bn = blockIdx.x * 128;
  const int tx = tid & 15;        // column group
  const int ty = tid >> 4;        // row group
  const int sr = tid >> 1;        // staging row 0..127
  const int sk = (tid & 1) * 8;   // staging k offset 0/8
  const float* Ap = A + (size_t)(bm + sr) * K + sk;
  const float* Bp = Bm + (size_t)(bn + sr) * K + sk;
  float acc[8][8];
#pragma unroll
  for (int i = 0; i < 8; ++i)
#pragma unroll
    for (int j = 0; j < 8; ++j) acc[i][j] = 0.f;

  for (int k0 = 0; k0 < K; k0 += 16) {
    const float4 a0 = *(const float4*)(Ap + k0);
    const float4 a1 = *(const float4*)(Ap + k0 + 4);
    const float4 b0 = *(const float4*)(Bp + k0);
    const float4 b1 = *(const float4*)(Bp + k0 + 4);
    __syncthreads();
    As[sk + 0][sr] = a0.x; As[sk + 1][sr] = a0.y;
    As[sk + 2][sr] = a0.z; As[sk + 3][sr] = a0.w;
    As[sk + 4][sr] = a1.x; As[sk + 5][sr] = a1.y;
    As[sk + 6][sr] = a1.z; As[sk + 7][sr] = a1.w;
    Bs[sk + 0][sr] = b0.x; Bs[sk + 1][sr] = b0.y;
    Bs[sk + 2][sr] = b0.z; Bs[sk + 3][sr] = b0.w;
    Bs[sk + 4][sr] = b1.x; Bs[sk + 5][sr] = b1.y;
    Bs[sk + 6][sr] = b1.z; Bs[sk + 7][sr] = b1.w;
    __syncthreads();
#pragma unroll
    for (int kk = 0; kk < 16; ++kk) {
      float av[8], bv[8];
      *(float4*)&av[0] = *(const float4*)&As[kk][ty * 8];
      *(float4*)&av[4] = *(const float4*)&As[kk][ty * 8 + 4];
      *(float4*)&bv[0] = *(const float4*)&Bs[kk][tx * 8];
      *(float4*)&bv[4] = *(const float4*)&Bs[kk][tx * 8 + 4];
#pragma unroll
      for (int i = 0; i < 8; ++i)
#pragma unroll
        for (int j = 0; j < 8; ++j) acc[i][j] = fmaf(av[i], bv[j], acc[i][j]);
    }
  }

  const float4 bs0 = *(const float4*)(bias + bn + tx * 8);
  const float4 bs1 = *(const float4*)(bias + bn + tx * 8 + 4);
#pragma unroll
  for (int i = 0; i < 8; ++i) {
    const size_t row = (size_t)(bm + ty * 8 + i);
    float* Crow = C + row * N + bn + tx * 8;
    float4 o0, o1;
    o0.x = acc[i][0] + bs0.x; o0.y = acc[i][1] + bs0.y;
    o0.z = acc[i][2] + bs0.z; o0.w = acc[i][3] + bs0.w;
    o1.x = acc[i][4] + bs1.x; o1.y = acc[i][5] + bs1.y;
    o1.z = acc[i][6] + bs1.z; o1.w = acc[i][7] + bs1.w;
    *(float4*)Crow = o0;
    *(float4*)(Crow + 4) = o1;
  }
}

// ---------------------------------------------------------------------------
// Per-(b,s,h) RMSNorm (q,k) + RoPE (q,k) + scatter to [B,H,S,64].
// One wave (64 lanes = head dim) per (b,s,h).
// ---------------------------------------------------------------------------
__global__ __launch_bounds__(256) void qkv_prep(
    const float* __restrict__ qkv, const float* __restrict__ q_scale,
    const float* __restrict__ k_scale, float* __restrict__ Qo,
    float* __restrict__ Ko, float* __restrict__ Vo) {
  const int lane = threadIdx.x & 63;
  const int gw = blockIdx.x * 4 + (threadIdx.x >> 6);  // global wave id
  const int h = gw & (CH - 1);
  const int s = (gw >> 4) & (CS - 1);
  const int b = gw >> 15;  // gw / (CH*CS)

  const size_t row = ((size_t)(b * CS + s)) * (3 * CDM) + (size_t)h * CHD + lane;
  float qv = qkv[row];
  float kv = qkv[row + CDM];
  const float vv = qkv[row + 2 * CDM];

  float sq = qv * qv, sk2 = kv * kv;
#pragma unroll
  for (int off = 32; off > 0; off >>= 1) {
    sq += __shfl_xor(sq, off);
    sk2 += __shfl_xor(sk2, off);
  }
  qv *= rsqrtf(sq * (1.f / CHD) + 1e-6f) * q_scale[lane];
  kv *= rsqrtf(sk2 * (1.f / CHD) + 1e-6f) * k_scale[lane];

  // RoPE: half-split rotary; angle index j = lane & 31, pos = s.
  const int j = lane & 31;
  const float inv = powf(10000.0f, -(float)j * (1.0f / 32.0f));
  const float ang = (float)s * inv;
  const float cs = cosf(ang);
  const float sn = sinf(ang);
  const float qp = __shfl_xor(qv, 32);
  const float kp = __shfl_xor(kv, 32);
  const float sgn = (lane < 32) ? -1.f : 1.f;
  const float qr = fmaf(qv, cs, sgn * qp * sn);
  const float kr = fmaf(kv, cs, sgn * kp * sn);

  const size_t ob = (((size_t)(b * CH + h)) * CS + s) * CHD + lane;
  Qo[ob] = qr;
  Ko[ob] = kr;
  Vo[ob] = vv;
}

// ---------------------------------------------------------------------------
// Flash-style frame-block-causal attention.
// Block = (frame pair fA=2*bx, fB=fA+1) x head x batch; 128 threads.
// Thread owns query rows sA (frame A) and sB (frame B), q & o in registers.
// Iterates allowed key frames, staging K,V frames (128x64 fp32) in LDS.
// Mask semantics: frame kf allowed iff kf <= f, except f==15 masks kf==0.
// exp(-1e30 - max) == 0 in fp32, so skipping masked frames is exact.
// ---------------------------------------------------------------------------
__global__ __launch_bounds__(128) void attn_fwd(
    const float* __restrict__ Qm, const float* __restrict__ Km,
    const float* __restrict__ Vm, float* __restrict__ Om) {
  __shared__ float4 Ks4[CTPF * 16];  // 32 KB
  __shared__ float4 Vs4[CTPF * 16];  // 32 KB
  const int tid = threadIdx.x;
  const int fA = blockIdx.x * 2;
  const int fB = fA + 1;
  const int h = blockIdx.y;
  const int b = blockIdx.z;
  const int sA = fA * CTPF + tid;
  const int sB = fB * CTPF + tid;
  const size_t hb = ((size_t)(b * CH + h)) * CS * CHD;

  const float4* QA = (const float4*)(Qm + hb + (size_t)sA * CHD);
  const float4* QB = (const float4*)(Qm + hb + (size_t)sB * CHD);
  float4 qa[16], qb[16], oa[16], ob[16];
#pragma unroll
  for (int t = 0; t < 16; ++t) {
    qa[t] = QA[t];
    qb[t] = QB[t];
    oa[t] = make_float4(0.f, 0.f, 0.f, 0.f);
    ob[t] = make_float4(0.f, 0.f, 0.f, 0.f);
  }
  float ma = -1e30f, la = 0.f, mb = -1e30f, lb = 0.f;

  for (int kf = 0; kf <= fB; ++kf) {
    __syncthreads();  // protect LDS from previous iteration's readers
    const float4* Kg = (const float4*)(Km + hb + (size_t)kf * CTPF * CHD);
    const float4* Vg = (const float4*)(Vm + hb + (size_t)kf * CTPF * CHD);
#pragma unroll
    for (int t = 0; t < 16; ++t) {
      Ks4[t * CTPF + tid] = Kg[t * CTPF + tid];
      Vs4[t * CTPF + tid] = Vg[t * CTPF + tid];
    }
    __syncthreads();
    const bool useA = (kf <= fA);                        // fA <= 14, no quirk
    const bool useB = !((fB == CNF - 1) && (kf == 0));   // last-frame quirk

    for (int jt = 0; jt < CTPF; jt += 16) {
      float sa[16], sb[16];
#pragma unroll
      for (int jj = 0; jj < 16; ++jj) {
        const float4* kr = &Ks4[(jt + jj) * 16];
        float da = 0.f, db = 0.f;
#pragma unroll
        for (int t = 0; t < 16; ++t) {
          const float4 kv = kr[t];
          da = fmaf(qa[t].x, kv.x, da);
          da = fmaf(qa[t].y, kv.y, da);
          da = fmaf(qa[t].z, kv.z, da);
          da = fmaf(qa[t].w, kv.w, da);
          db = fmaf(qb[t].x, kv.x, db);
          db = fmaf(qb[t].y, kv.y, db);
          db = fmaf(qb[t].z, kv.z, db);
          db = fmaf(qb[t].w, kv.w, db);
        }
        sa[jj] = da * 0.125f;  // HD^-0.5
        sb[jj] = db * 0.125f;
      }
      if (useA) {
        float tm = sa[0];
#pragma unroll
        for (int jj = 1; jj < 16; ++jj) tm = fmaxf(tm, sa[jj]);
        const float mn = fmaxf(ma, tm);
        const float c = __expf(ma - mn);
        la *= c;
        ma = mn;
#pragma unroll
        for (int t = 0; t < 16; ++t) {
          oa[t].x *= c; oa[t].y *= c; oa[t].z *= c; oa[t].w *= c;
        }
      }
      if (useB) {
        float tm = sb[0];
#pragma unroll
        for (int jj = 1; jj < 16; ++jj) tm = fmaxf(tm, sb[jj]);
        const float mn = fmaxf(mb, tm);
        const float c = __expf(mb - mn);
        lb *= c;
        mb = mn;
#pragma unroll
        for (int t = 0; t < 16; ++t) {
          ob[t].x *= c; ob[t].y *= c; ob[t].z *= c; ob[t].w *= c;
        }
      }
#pragma unroll
      for (int jj = 0; jj < 16; ++jj) {
        const float pa = useA ? __expf(sa[jj] - ma) : 0.f;
        const float pb = useB ? __expf(sb[jj] - mb) : 0.f;
        la += pa;
        lb += pb;
        const float4* vr = &Vs4[(jt + jj) * 16];
#pragma unroll
        for (int t = 0; t < 16; ++t) {
          const float4 v = vr[t];
          oa[t].x = fmaf(pa, v.x, oa[t].x);
          oa[t].y = fmaf(pa, v.y, oa[t].y);
          oa[t].z = fmaf(pa, v.z, oa[t].z);
          oa[t].w = fmaf(pa, v.w, oa[t].w);
          ob[t].x = fmaf(pb, v.x, ob[t].x);
          ob[t].y = fmaf(pb, v.y, ob[t].y);
          ob[t].z = fmaf(pb, v.z, ob[t].z);
          ob[t].w = fmaf(pb, v.w, ob[t].w);
        }
      }
    }
  }

  const float ia = 1.f / la;
  const float ib = 1.f / lb;
  // Write attention output directly in [B,S,DM] layout for the out-projection.
  float4* OA = (float4*)(Om + ((size_t)(b * CS + sA)) * CDM + (size_t)h * CHD);
  float4* OB = (float4*)(Om + ((size_t)(b * CS + sB)) * CDM + (size_t)h * CHD);
#pragma unroll
  for (int t = 0; t < 16; ++t) {
    float4 va = oa[t], vb = ob[t];
    va.x *= ia; va.y *= ia; va.z *= ia; va.w *= ia;
    vb.x *= ib; vb.y *= ib; vb.z *= ib; vb.w *= ib;
    OA[t] = va;
    OB[t] = vb;
  }
}

// ---------------------------------------------------------------------------
extern "C" void kernel_launch(void* const* d_in, const int* in_sizes, int n_in,
                              void* d_out, int out_size, void* d_ws, size_t ws_size,
                              hipStream_t stream) {
  const float* x       = (const float*)d_in[0];
  const float* Wqkv    = (const float*)d_in[1];
  const float* bqkv    = (const float*)d_in[2];
  const float* q_scale = (const float*)d_in[3];
  const float* k_scale = (const float*)d_in[4];
  const float* Wout    = (const float*)d_in[5];
  const float* bout    = (const float*)d_in[6];
  float* out = (float*)d_out;

  float* ws = (float*)d_ws;
  float* qkv = ws;                                   // [4096, 3072]
  float* Qb = ws + (size_t)(CB * CS) * (3 * CDM);    // [B,H,S,64] each
  float* Kb = Qb + (size_t)CB * CH * CS * CHD;
  float* Vb = Kb + (size_t)CB * CH * CS * CHD;
  float* AO = ws;  // attention output [B,S,DM]; aliases qkv (dead after prep)

  // 1) qkv = x @ Wqkv^T + bqkv
  dim3 g1((3 * CDM) / 128, (CB * CS) / 128);
  gemm_bt_bias<<<g1, 256, 0, stream>>>(x, Wqkv, bqkv, qkv, CB * CS, 3 * CDM, CDM);

  // 2) RMSNorm + RoPE + scatter to [B,H,S,64]
  qkv_prep<<<(CB * CS * CH) / 4, 256, 0, stream>>>(qkv, q_scale, k_scale, Qb, Kb, Vb);

  // 3) frame-block-causal attention
  dim3 g3(CNF / 2, CH, CB);
  attn_fwd<<<g3, 128, 0, stream>>>(Qb, Kb, Vb, AO);

  // 4) out = AO @ Wout^T + bout
  dim3 g4(CDM / 128, (CB * CS) / 128);
  gemm_bt_bias<<<g4, 256, 0, stream>>>(AO, Wout, bout, out, CB * CS, CDM, CDM);
}

// Round 5
// 1542.571 us; speedup vs baseline: 6.6131x; 6.6131x over previous
//
#include <hip/hip_runtime.h>
#include <cstddef>
#include <cstdint>

// Problem constants (match reference)
constexpr int CB  = 2;     // batch
constexpr int CS  = 2048;  // seq len
constexpr int CDM = 1024;  // d_model
constexpr int CH  = 16;    // heads
constexpr int CHD = 64;    // head dim
constexpr int CTPF = 128;  // tokens per frame
constexpr int CNF = 16;    // frames

// ---------------------------------------------------------------------------
// GEMM: C[M,N] = A[M,K] @ B[N,K]^T + bias[N]
// 128x128 tile, BK=16, 256 threads, 8x8 micro-tile, LDS stored [k][row].
// ---------------------------------------------------------------------------
__global__ __launch_bounds__(256) void gemm_bt_bias(
    const float* __restrict__ A, const float* __restrict__ Bm,
    const float* __restrict__ bias, float* __restrict__ C,
    int M, int N, int K) {
  __shared__ float As[16][128];
  __shared__ float Bs[16][128];
  const int tid = threadIdx.x;
  const int bm = blockIdx.y * 128;
  const int bn = blockIdx.x * 128;
  const int tx = tid & 15;        // column group
  const int ty = tid >> 4;        // row group
  const int sr = tid >> 1;        // staging row 0..127
  const int sk = (tid & 1) * 8;   // staging k offset 0/8
  const float* Ap = A + (size_t)(bm + sr) * K + sk;
  const float* Bp = Bm + (size_t)(bn + sr) * K + sk;
  float acc[8][8];
#pragma unroll
  for (int i = 0; i < 8; ++i)
#pragma unroll
    for (int j = 0; j < 8; ++j) acc[i][j] = 0.f;

  for (int k0 = 0; k0 < K; k0 += 16) {
    const float4 a0 = *(const float4*)(Ap + k0);
    const float4 a1 = *(const float4*)(Ap + k0 + 4);
    const float4 b0 = *(const float4*)(Bp + k0);
    const float4 b1 = *(const float4*)(Bp + k0 + 4);
    __syncthreads();
    As[sk + 0][sr] = a0.x; As[sk + 1][sr] = a0.y;
    As[sk + 2][sr] = a0.z; As[sk + 3][sr] = a0.w;
    As[sk + 4][sr] = a1.x; As[sk + 5][sr] = a1.y;
    As[sk + 6][sr] = a1.z; As[sk + 7][sr] = a1.w;
    Bs[sk + 0][sr] = b0.x; Bs[sk + 1][sr] = b0.y;
    Bs[sk + 2][sr] = b0.z; Bs[sk + 3][sr] = b0.w;
    Bs[sk + 4][sr] = b1.x; Bs[sk + 5][sr] = b1.y;
    Bs[sk + 6][sr] = b1.z; Bs[sk + 7][sr] = b1.w;
    __syncthreads();
#pragma unroll
    for (int kk = 0; kk < 16; ++kk) {
      float av[8], bv[8];
      *(float4*)&av[0] = *(const float4*)&As[kk][ty * 8];
      *(float4*)&av[4] = *(const float4*)&As[kk][ty * 8 + 4];
      *(float4*)&bv[0] = *(const float4*)&Bs[kk][tx * 8];
      *(float4*)&bv[4] = *(const float4*)&Bs[kk][tx * 8 + 4];
#pragma unroll
      for (int i = 0; i < 8; ++i)
#pragma unroll
        for (int j = 0; j < 8; ++j) acc[i][j] = fmaf(av[i], bv[j], acc[i][j]);
    }
  }

  const float4 bs0 = *(const float4*)(bias + bn + tx * 8);
  const float4 bs1 = *(const float4*)(bias + bn + tx * 8 + 4);
#pragma unroll
  for (int i = 0; i < 8; ++i) {
    const size_t row = (size_t)(bm + ty * 8 + i);
    float* Crow = C + row * N + bn + tx * 8;
    float4 o0, o1;
    o0.x = acc[i][0] + bs0.x; o0.y = acc[i][1] + bs0.y;
    o0.z = acc[i][2] + bs0.z; o0.w = acc[i][3] + bs0.w;
    o1.x = acc[i][4] + bs1.x; o1.y = acc[i][5] + bs1.y;
    o1.z = acc[i][6] + bs1.z; o1.w = acc[i][7] + bs1.w;
    *(float4*)Crow = o0;
    *(float4*)(Crow + 4) = o1;
  }
}

// ---------------------------------------------------------------------------
// Per-(b,s,h) RMSNorm (q,k) + RoPE (q,k) + scatter to [B,H,S,64].
// One wave (64 lanes = head dim) per (b,s,h).
// ---------------------------------------------------------------------------
__global__ __launch_bounds__(256) void qkv_prep(
    const float* __restrict__ qkv, const float* __restrict__ q_scale,
    const float* __restrict__ k_scale, float* __restrict__ Qo,
    float* __restrict__ Ko, float* __restrict__ Vo) {
  const int lane = threadIdx.x & 63;
  const int gw = blockIdx.x * 4 + (threadIdx.x >> 6);  // global wave id
  const int h = gw & (CH - 1);
  const int s = (gw >> 4) & (CS - 1);
  const int b = gw >> 15;  // gw / (CH*CS)

  const size_t row = ((size_t)(b * CS + s)) * (3 * CDM) + (size_t)h * CHD + lane;
  float qv = qkv[row];
  float kv = qkv[row + CDM];
  const float vv = qkv[row + 2 * CDM];

  float sq = qv * qv, sk2 = kv * kv;
#pragma unroll
  for (int off = 32; off > 0; off >>= 1) {
    sq += __shfl_xor(sq, off);
    sk2 += __shfl_xor(sk2, off);
  }
  qv *= rsqrtf(sq * (1.f / CHD) + 1e-6f) * q_scale[lane];
  kv *= rsqrtf(sk2 * (1.f / CHD) + 1e-6f) * k_scale[lane];

  // RoPE: half-split rotary; angle index j = lane & 31, pos = s.
  const int j = lane & 31;
  const float inv = powf(10000.0f, -(float)j * (1.0f / 32.0f));
  const float ang = (float)s * inv;
  const float cs = cosf(ang);
  const float sn = sinf(ang);
  const float qp = __shfl_xor(qv, 32);
  const float kp = __shfl_xor(kv, 32);
  const float sgn = (lane < 32) ? -1.f : 1.f;
  const float qr = fmaf(qv, cs, sgn * qp * sn);
  const float kr = fmaf(kv, cs, sgn * kp * sn);

  const size_t ob = (((size_t)(b * CH + h)) * CS + s) * CHD + lane;
  Qo[ob] = qr;
  Ko[ob] = kr;
  Vo[ob] = vv;
}

// ---------------------------------------------------------------------------
// Flash-style frame-block-causal attention, v2.
// One block per (query frame f, head, batch): 512 blocks, 128 threads.
// Thread t owns ONE query row s = f*128 + t (q, o fully in registers:
// 64+64 = 128 VGPR of state -> no spill, unlike v1's 2-rows/thread = 256+).
// Mask is block-uniform: frame f attends key frames [0..f], except the
// last frame (f==15) which skips frame 0 (the reference "quirk"); the NEG
// mask value underflows to exactly 0 through softmax, so skipping is exact.
// K/V staged in 64-key chunks (2x16KB LDS). All lanes read the same K/V row
// address in lockstep -> LDS broadcast, no bank conflicts.
// Heavy-first block order: f = 15 - blockIdx.x.
// ---------------------------------------------------------------------------
__global__ __launch_bounds__(128) void attn_fwd(
    const float* __restrict__ Qm, const float* __restrict__ Km,
    const float* __restrict__ Vm, float* __restrict__ Om) {
  __shared__ float4 Ks4[64 * 16];  // 16 KB: 64 keys x 64 dims
  __shared__ float4 Vs4[64 * 16];  // 16 KB
  const int tid = threadIdx.x;
  const int f = (CNF - 1) - blockIdx.x;  // heavy frames launch first
  const int h = blockIdx.y;
  const int b = blockIdx.z;
  const int s = f * CTPF + tid;
  const size_t hb = ((size_t)(b * CH + h)) * CS * CHD;

  const float4* Qp = (const float4*)(Qm + hb + (size_t)s * CHD);
  float4 q[16], o[16];
#pragma unroll
  for (int t = 0; t < 16; ++t) {
    q[t] = Qp[t];
    o[t] = make_float4(0.f, 0.f, 0.f, 0.f);
  }
  float m = -1e30f, l = 0.f;

  const int kf0 = (f == CNF - 1) ? 1 : 0;  // last-frame quirk: skip frame 0
  for (int kf = kf0; kf <= f; ++kf) {
    for (int half = 0; half < 2; ++half) {
      __syncthreads();  // protect LDS from previous chunk's readers
      const float4* Kg =
          (const float4*)(Km + hb + ((size_t)kf * CTPF + half * 64) * CHD);
      const float4* Vg =
          (const float4*)(Vm + hb + ((size_t)kf * CTPF + half * 64) * CHD);
#pragma unroll
      for (int i = 0; i < 8; ++i) {
        Ks4[i * 128 + tid] = Kg[i * 128 + tid];
        Vs4[i * 128 + tid] = Vg[i * 128 + tid];
      }
      __syncthreads();

      for (int j0 = 0; j0 < 64; j0 += 16) {
        float sc[16];
#pragma unroll
        for (int jj = 0; jj < 16; ++jj) {
          const float4* kr = &Ks4[(j0 + jj) * 16];
          float d = 0.f;
#pragma unroll
          for (int t = 0; t < 16; ++t) {
            const float4 kv = kr[t];
            d = fmaf(q[t].x, kv.x, d);
            d = fmaf(q[t].y, kv.y, d);
            d = fmaf(q[t].z, kv.z, d);
            d = fmaf(q[t].w, kv.w, d);
          }
          sc[jj] = d * 0.125f;  // HD^-0.5
        }
        float tm = sc[0];
#pragma unroll
        for (int jj = 1; jj < 16; ++jj) tm = fmaxf(tm, sc[jj]);
        if (tm > m) {  // defer-max: rescale only when the max actually grows
          const float c = __expf(m - tm);
          l *= c;
          m = tm;
#pragma unroll
          for (int t = 0; t < 16; ++t) {
            o[t].x *= c; o[t].y *= c; o[t].z *= c; o[t].w *= c;
          }
        }
#pragma unroll
        for (int jj = 0; jj < 16; ++jj) {
          const float p = __expf(sc[jj] - m);
          l += p;
          const float4* vr = &Vs4[(j0 + jj) * 16];
#pragma unroll
          for (int t = 0; t < 16; ++t) {
            const float4 v = vr[t];
            o[t].x = fmaf(p, v.x, o[t].x);
            o[t].y = fmaf(p, v.y, o[t].y);
            o[t].z = fmaf(p, v.z, o[t].z);
            o[t].w = fmaf(p, v.w, o[t].w);
          }
        }
      }
    }
  }

  const float inv = 1.f / l;
  // Write attention output directly in [B,S,DM] layout for the out-projection.
  float4* Op = (float4*)(Om + ((size_t)(b * CS + s)) * CDM + (size_t)h * CHD);
#pragma unroll
  for (int t = 0; t < 16; ++t) {
    float4 v = o[t];
    v.x *= inv; v.y *= inv; v.z *= inv; v.w *= inv;
    Op[t] = v;
  }
}

// ---------------------------------------------------------------------------
extern "C" void kernel_launch(void* const* d_in, const int* in_sizes, int n_in,
                              void* d_out, int out_size, void* d_ws, size_t ws_size,
                              hipStream_t stream) {
  const float* x       = (const float*)d_in[0];
  const float* Wqkv    = (const float*)d_in[1];
  const float* bqkv    = (const float*)d_in[2];
  const float* q_scale = (const float*)d_in[3];
  const float* k_scale = (const float*)d_in[4];
  const float* Wout    = (const float*)d_in[5];
  const float* bout    = (const float*)d_in[6];
  float* out = (float*)d_out;

  float* ws = (float*)d_ws;
  float* qkv = ws;                                   // [4096, 3072]
  float* Qb = ws + (size_t)(CB * CS) * (3 * CDM);    // [B,H,S,64] each
  float* Kb = Qb + (size_t)CB * CH * CS * CHD;
  float* Vb = Kb + (size_t)CB * CH * CS * CHD;
  float* AO = ws;  // attention output [B,S,DM]; aliases qkv (dead after prep)

  // 1) qkv = x @ Wqkv^T + bqkv
  dim3 g1((3 * CDM) / 128, (CB * CS) / 128);
  gemm_bt_bias<<<g1, 256, 0, stream>>>(x, Wqkv, bqkv, qkv, CB * CS, 3 * CDM, CDM);

  // 2) RMSNorm + RoPE + scatter to [B,H,S,64]
  qkv_prep<<<(CB * CS * CH) / 4, 256, 0, stream>>>(qkv, q_scale, k_scale, Qb, Kb, Vb);

  // 3) frame-block-causal attention (one block per frame x head x batch)
  dim3 g3(CNF, CH, CB);
  attn_fwd<<<g3, 128, 0, stream>>>(Qb, Kb, Vb, AO);

  // 4) out = AO @ Wout^T + bout
  dim3 g4(CDM / 128, (CB * CS) / 128);
  gemm_bt_bias<<<g4, 256, 0, stream>>>(AO, Wout, bout, out, CB * CS, CDM, CDM);
}

// Round 6
// 1095.178 us; speedup vs baseline: 9.3147x; 1.4085x over previous
//
#include <hip/hip_runtime.h>
#include <cstddef>
#include <cstdint>

// Problem constants (match reference)
constexpr int CB  = 2;     // batch
constexpr int CS  = 2048;  // seq len
constexpr int CDM = 1024;  // d_model
constexpr int CH  = 16;    // heads
constexpr int CHD = 64;    // head dim
constexpr int CTPF = 128;  // tokens per frame
constexpr int CNF = 16;    // frames

// ---------------------------------------------------------------------------
// GEMM: C[M,N] = A[M,K] @ B[N,K]^T + bias[N]
// 128x128 tile, BK=16, 256 threads, 8x8 micro-tile, LDS stored [k][row].
// ---------------------------------------------------------------------------
__global__ __launch_bounds__(256) void gemm_bt_bias(
    const float* __restrict__ A, const float* __restrict__ Bm,
    const float* __restrict__ bias, float* __restrict__ C,
    int M, int N, int K) {
  __shared__ float As[16][128];
  __shared__ float Bs[16][128];
  const int tid = threadIdx.x;
  const int bm = blockIdx.y * 128;
  const int bn = blockIdx.x * 128;
  const int tx = tid & 15;        // column group
  const int ty = tid >> 4;        // row group
  const int sr = tid >> 1;        // staging row 0..127
  const int sk = (tid & 1) * 8;   // staging k offset 0/8
  const float* Ap = A + (size_t)(bm + sr) * K + sk;
  const float* Bp = Bm + (size_t)(bn + sr) * K + sk;
  float acc[8][8];
#pragma unroll
  for (int i = 0; i < 8; ++i)
#pragma unroll
    for (int j = 0; j < 8; ++j) acc[i][j] = 0.f;

  for (int k0 = 0; k0 < K; k0 += 16) {
    const float4 a0 = *(const float4*)(Ap + k0);
    const float4 a1 = *(const float4*)(Ap + k0 + 4);
    const float4 b0 = *(const float4*)(Bp + k0);
    const float4 b1 = *(const float4*)(Bp + k0 + 4);
    __syncthreads();
    As[sk + 0][sr] = a0.x; As[sk + 1][sr] = a0.y;
    As[sk + 2][sr] = a0.z; As[sk + 3][sr] = a0.w;
    As[sk + 4][sr] = a1.x; As[sk + 5][sr] = a1.y;
    As[sk + 6][sr] = a1.z; As[sk + 7][sr] = a1.w;
    Bs[sk + 0][sr] = b0.x; Bs[sk + 1][sr] = b0.y;
    Bs[sk + 2][sr] = b0.z; Bs[sk + 3][sr] = b0.w;
    Bs[sk + 4][sr] = b1.x; Bs[sk + 5][sr] = b1.y;
    Bs[sk + 6][sr] = b1.z; Bs[sk + 7][sr] = b1.w;
    __syncthreads();
#pragma unroll
    for (int kk = 0; kk < 16; ++kk) {
      float av[8], bv[8];
      *(float4*)&av[0] = *(const float4*)&As[kk][ty * 8];
      *(float4*)&av[4] = *(const float4*)&As[kk][ty * 8 + 4];
      *(float4*)&bv[0] = *(const float4*)&Bs[kk][tx * 8];
      *(float4*)&bv[4] = *(const float4*)&Bs[kk][tx * 8 + 4];
#pragma unroll
      for (int i = 0; i < 8; ++i)
#pragma unroll
        for (int j = 0; j < 8; ++j) acc[i][j] = fmaf(av[i], bv[j], acc[i][j]);
    }
  }

  const float4 bs0 = *(const float4*)(bias + bn + tx * 8);
  const float4 bs1 = *(const float4*)(bias + bn + tx * 8 + 4);
#pragma unroll
  for (int i = 0; i < 8; ++i) {
    const size_t row = (size_t)(bm + ty * 8 + i);
    float* Crow = C + row * N + bn + tx * 8;
    float4 o0, o1;
    o0.x = acc[i][0] + bs0.x; o0.y = acc[i][1] + bs0.y;
    o0.z = acc[i][2] + bs0.z; o0.w = acc[i][3] + bs0.w;
    o1.x = acc[i][4] + bs1.x; o1.y = acc[i][5] + bs1.y;
    o1.z = acc[i][6] + bs1.z; o1.w = acc[i][7] + bs1.w;
    *(float4*)Crow = o0;
    *(float4*)(Crow + 4) = o1;
  }
}

// ---------------------------------------------------------------------------
// Per-(b,s,h) RMSNorm (q,k) + RoPE (q,k) + scatter to [B,H,S,64].
// One wave (64 lanes = head dim) per (b,s,h).
// ---------------------------------------------------------------------------
__global__ __launch_bounds__(256) void qkv_prep(
    const float* __restrict__ qkv, const float* __restrict__ q_scale,
    const float* __restrict__ k_scale, float* __restrict__ Qo,
    float* __restrict__ Ko, float* __restrict__ Vo) {
  const int lane = threadIdx.x & 63;
  const int gw = blockIdx.x * 4 + (threadIdx.x >> 6);  // global wave id
  const int h = gw & (CH - 1);
  const int s = (gw >> 4) & (CS - 1);
  const int b = gw >> 15;  // gw / (CH*CS)

  const size_t row = ((size_t)(b * CS + s)) * (3 * CDM) + (size_t)h * CHD + lane;
  float qv = qkv[row];
  float kv = qkv[row + CDM];
  const float vv = qkv[row + 2 * CDM];

  float sq = qv * qv, sk2 = kv * kv;
#pragma unroll
  for (int off = 32; off > 0; off >>= 1) {
    sq += __shfl_xor(sq, off);
    sk2 += __shfl_xor(sk2, off);
  }
  qv *= rsqrtf(sq * (1.f / CHD) + 1e-6f) * q_scale[lane];
  kv *= rsqrtf(sk2 * (1.f / CHD) + 1e-6f) * k_scale[lane];

  // RoPE: half-split rotary; angle index j = lane & 31, pos = s.
  const int j = lane & 31;
  const float inv = powf(10000.0f, -(float)j * (1.0f / 32.0f));
  const float ang = (float)s * inv;
  const float cs = cosf(ang);
  const float sn = sinf(ang);
  const float qp = __shfl_xor(qv, 32);
  const float kp = __shfl_xor(kv, 32);
  const float sgn = (lane < 32) ? -1.f : 1.f;
  const float qr = fmaf(qv, cs, sgn * qp * sn);
  const float kr = fmaf(kv, cs, sgn * kp * sn);

  const size_t ob = (((size_t)(b * CH + h)) * CS + s) * CHD + lane;
  Qo[ob] = qr;
  Ko[ob] = kr;
  Vo[ob] = vv;
}

// ---------------------------------------------------------------------------
// Flash-style frame-block-causal attention, v3 (dim-split lane pairs).
// v2 diagnosis: 512 blocks x 2 waves = 1 wave/SIMD, VALUBusy 16.5% -->
// issue/latency-bound. v3: each query's 64 dims are split across lane pair
// (lane, lane^32) inside one wave; a wave covers 32 queries x 32 dims.
//   - per key per wave: 8 ds_read_b128 + 32 FMA (half of v2) + 1 shfl_xor
//   - block = 128 threads (2 waves) = 64 queries -> grid 1024 blocks
//     = 8 waves/CU = 2 waves/SIMD (2x occupancy)
//   - q/o register state halves: ~16 VGPR less pressure
// Mask semantics unchanged: frame f attends key frames [0..f], except
// f==15 skips frame 0 (reference quirk; exact because exp underflows to 0).
// ---------------------------------------------------------------------------
__global__ __launch_bounds__(128) void attn_fwd(
    const float* __restrict__ Qm, const float* __restrict__ Km,
    const float* __restrict__ Vm, float* __restrict__ Om) {
  __shared__ float4 Ks4[64 * 16];  // 16 KB: 64 keys x 64 dims
  __shared__ float4 Vs4[64 * 16];  // 16 KB
  const int tid = threadIdx.x;
  const int qhalf = blockIdx.x & 1;            // which 64 queries of the frame
  const int f = (CNF - 1) - (blockIdx.x >> 1); // heavy frames launch first
  const int h = blockIdx.y;
  const int b = blockIdx.z;
  const int qi = qhalf * 64 + (tid >> 6) * 32 + (tid & 31);  // query in frame
  const int dh = (tid >> 5) & 1;                             // dim half 0/1
  const int s = f * CTPF + qi;
  const size_t hb = ((size_t)(b * CH + h)) * CS * CHD;

  // q: this lane's 32 dims of its query row.
  const float4* Qp = (const float4*)(Qm + hb + (size_t)s * CHD) + dh * 8;
  float4 q[8], o[8];
#pragma unroll
  for (int t = 0; t < 8; ++t) {
    q[t] = Qp[t];
    o[t] = make_float4(0.f, 0.f, 0.f, 0.f);
  }
  float m = -1e30f, l = 0.f;

  const int kf0 = (f == CNF - 1) ? 1 : 0;  // last-frame quirk: skip frame 0
  for (int kf = kf0; kf <= f; ++kf) {
    for (int half = 0; half < 2; ++half) {
      __syncthreads();  // protect LDS from previous chunk's readers
      const float4* Kg =
          (const float4*)(Km + hb + ((size_t)kf * CTPF + half * 64) * CHD);
      const float4* Vg =
          (const float4*)(Vm + hb + ((size_t)kf * CTPF + half * 64) * CHD);
#pragma unroll
      for (int i = 0; i < 8; ++i) {
        Ks4[i * 128 + tid] = Kg[i * 128 + tid];
        Vs4[i * 128 + tid] = Vg[i * 128 + tid];
      }
      __syncthreads();

      for (int j0 = 0; j0 < 64; j0 += 16) {
        float sc[16];
#pragma unroll
        for (int jj = 0; jj < 16; ++jj) {
          const float4* kr = &Ks4[(j0 + jj) * 16 + dh * 8];
          float d = 0.f;
#pragma unroll
          for (int t = 0; t < 8; ++t) {
            const float4 kv = kr[t];
            d = fmaf(q[t].x, kv.x, d);
            d = fmaf(q[t].y, kv.y, d);
            d = fmaf(q[t].z, kv.z, d);
            d = fmaf(q[t].w, kv.w, d);
          }
          // combine the two half-dim partial dots; both pair lanes get the sum
          d += __shfl_xor(d, 32);
          sc[jj] = d * 0.125f;  // HD^-0.5
        }
        float tm = sc[0];
#pragma unroll
        for (int jj = 1; jj < 16; ++jj) tm = fmaxf(tm, sc[jj]);
        if (tm > m) {  // defer-max: rescale only when the max actually grows
          const float c = __expf(m - tm);
          l *= c;
          m = tm;
#pragma unroll
          for (int t = 0; t < 8; ++t) {
            o[t].x *= c; o[t].y *= c; o[t].z *= c; o[t].w *= c;
          }
        }
#pragma unroll
        for (int jj = 0; jj < 16; ++jj) {
          const float p = __expf(sc[jj] - m);
          l += p;  // pair lanes accumulate identical l
          const float4* vr = &Vs4[(j0 + jj) * 16 + dh * 8];
#pragma unroll
          for (int t = 0; t < 8; ++t) {
            const float4 v = vr[t];
            o[t].x = fmaf(p, v.x, o[t].x);
            o[t].y = fmaf(p, v.y, o[t].y);
            o[t].z = fmaf(p, v.z, o[t].z);
            o[t].w = fmaf(p, v.w, o[t].w);
          }
        }
      }
    }
  }

  const float inv = 1.f / l;
  // Write this lane's 32 dims directly in [B,S,DM] layout.
  float4* Op =
      (float4*)(Om + ((size_t)(b * CS + s)) * CDM + (size_t)h * CHD) + dh * 8;
#pragma unroll
  for (int t = 0; t < 8; ++t) {
    float4 v = o[t];
    v.x *= inv; v.y *= inv; v.z *= inv; v.w *= inv;
    Op[t] = v;
  }
}

// ---------------------------------------------------------------------------
extern "C" void kernel_launch(void* const* d_in, const int* in_sizes, int n_in,
                              void* d_out, int out_size, void* d_ws, size_t ws_size,
                              hipStream_t stream) {
  const float* x       = (const float*)d_in[0];
  const float* Wqkv    = (const float*)d_in[1];
  const float* bqkv    = (const float*)d_in[2];
  const float* q_scale = (const float*)d_in[3];
  const float* k_scale = (const float*)d_in[4];
  const float* Wout    = (const float*)d_in[5];
  const float* bout    = (const float*)d_in[6];
  float* out = (float*)d_out;

  float* ws = (float*)d_ws;
  float* qkv = ws;                                   // [4096, 3072]
  float* Qb = ws + (size_t)(CB * CS) * (3 * CDM);    // [B,H,S,64] each
  float* Kb = Qb + (size_t)CB * CH * CS * CHD;
  float* Vb = Kb + (size_t)CB * CH * CS * CHD;
  float* AO = ws;  // attention output [B,S,DM]; aliases qkv (dead after prep)

  // 1) qkv = x @ Wqkv^T + bqkv
  dim3 g1((3 * CDM) / 128, (CB * CS) / 128);
  gemm_bt_bias<<<g1, 256, 0, stream>>>(x, Wqkv, bqkv, qkv, CB * CS, 3 * CDM, CDM);

  // 2) RMSNorm + RoPE + scatter to [B,H,S,64]
  qkv_prep<<<(CB * CS * CH) / 4, 256, 0, stream>>>(qkv, q_scale, k_scale, Qb, Kb, Vb);

  // 3) frame-block-causal attention (two blocks per frame x head x batch)
  dim3 g3(CNF * 2, CH, CB);
  attn_fwd<<<g3, 128, 0, stream>>>(Qb, Kb, Vb, AO);

  // 4) out = AO @ Wout^T + bout
  dim3 g4(CDM / 128, (CB * CS) / 128);
  gemm_bt_bias<<<g4, 256, 0, stream>>>(AO, Wout, bout, out, CB * CS, CDM, CDM);
}

// Round 7
// 838.816 us; speedup vs baseline: 12.1615x; 1.3056x over previous
//
#include <hip/hip_runtime.h>
#include <cstddef>
#include <cstdint>

// Problem constants (match reference)
constexpr int CB  = 2;     // batch
constexpr int CS  = 2048;  // seq len
constexpr int CDM = 1024;  // d_model
constexpr int CH  = 16;    // heads
constexpr int CHD = 64;    // head dim
constexpr int CTPF = 128;  // tokens per frame
constexpr int CNF = 16;    // frames

typedef __attribute__((ext_vector_type(8))) short short8;
typedef __attribute__((ext_vector_type(4))) float f32x4;

__device__ inline ushort f32_bf16_rne(float x) {
  uint32_t u = __float_as_uint(x);
  u += 0x7FFFu + ((u >> 16) & 1u);
  return (ushort)(u >> 16);
}
__device__ inline float bf16_f32(ushort h) {
  return __uint_as_float(((uint32_t)h) << 16);
}

// ---------------------------------------------------------------------------
// GEMM: C[M,N] = A[M,K] @ B[N,K]^T + bias[N], split-bf16 MFMA.
// fp32 inputs are split in-kernel during staging: a = ah + al (bf16 each);
// product = ah*bh + ah*bl + al*bh (al*bl dropped, ~2^-18 rel) -> 3 MFMA per
// logical op at bf16 rate (~2.4 PF) vs fp32 VALU (157 TF).
// Tile 128x128, BK=32, 256 thr = 4 waves (2x2), wave tile 64x64 = 4x4 frags
// of v_mfma_f32_16x16x32_bf16.
// Fragment layout: M/N index = lane&15 (m89-verified C/D: col=lane&15,
// row=(lane>>4)*4+i). A and B k-slots use the IDENTICAL (lane>>4)*8+i
// formula, so any HW k-permutation cancels between operands.
// LDS row stride 40 bf16 (80 B): frag-read lanes r and r+8 alias the same
// bank pair -> 2-way conflict only (free, m136).
// ---------------------------------------------------------------------------
constexpr int SP = 40;  // LDS row stride in bf16 elements (32 + 8 pad)

__global__ __launch_bounds__(256) void gemm_bt_bias_mfma(
    const float* __restrict__ A, const float* __restrict__ Bm,
    const float* __restrict__ bias, float* __restrict__ C,
    int M, int N, int K) {
  __shared__ ushort As_h[128 * SP];  // 10 KB each, 40 KB total
  __shared__ ushort As_l[128 * SP];
  __shared__ ushort Bs_h[128 * SP];
  __shared__ ushort Bs_l[128 * SP];
  const int tid = threadIdx.x;
  const int bm = blockIdx.y * 128;
  const int bn = blockIdx.x * 128;
  const int wid = tid >> 6;
  const int lane = tid & 63;
  const int wm = wid >> 1;          // wave row 0..1
  const int wn = wid & 1;           // wave col 0..1
  const int l15 = lane & 15;
  const int lk = lane >> 4;         // k-group 0..3

  f32x4 acc[4][4];
#pragma unroll
  for (int i = 0; i < 4; ++i)
#pragma unroll
    for (int j = 0; j < 4; ++j) acc[i][j] = (f32x4){0.f, 0.f, 0.f, 0.f};

  for (int k0 = 0; k0 < K; k0 += 32) {
    __syncthreads();  // protect LDS from previous iteration's readers
#pragma unroll
    for (int c = 0; c < 2; ++c) {
      const int lin = tid + c * 256;   // 0..511
      const int row = lin >> 2;        // 0..127
      const int kq = (lin & 3) * 8;    // 0,8,16,24
      // A chunk: 8 floats -> hi/lo bf16
      const float* ap = A + (size_t)(bm + row) * K + k0 + kq;
      const float4 a0 = *(const float4*)ap;
      const float4 a1 = *(const float4*)(ap + 4);
      const float va[8] = {a0.x, a0.y, a0.z, a0.w, a1.x, a1.y, a1.z, a1.w};
      short8 hv, lv;
#pragma unroll
      for (int j = 0; j < 8; ++j) {
        const ushort h = f32_bf16_rne(va[j]);
        hv[j] = (short)h;
        lv[j] = (short)f32_bf16_rne(va[j] - bf16_f32(h));
      }
      *(short8*)&As_h[row * SP + kq] = hv;
      *(short8*)&As_l[row * SP + kq] = lv;
      // B chunk
      const float* bp = Bm + (size_t)(bn + row) * K + k0 + kq;
      const float4 b0 = *(const float4*)bp;
      const float4 b1 = *(const float4*)(bp + 4);
      const float vb[8] = {b0.x, b0.y, b0.z, b0.w, b1.x, b1.y, b1.z, b1.w};
#pragma unroll
      for (int j = 0; j < 8; ++j) {
        const ushort h = f32_bf16_rne(vb[j]);
        hv[j] = (short)h;
        lv[j] = (short)f32_bf16_rne(vb[j] - bf16_f32(h));
      }
      *(short8*)&Bs_h[row * SP + kq] = hv;
      *(short8*)&Bs_l[row * SP + kq] = lv;
    }
    __syncthreads();

    short8 ah[4], al[4], bh[4], bl[4];
#pragma unroll
    for (int f = 0; f < 4; ++f) {
      const int ar = wm * 64 + f * 16 + l15;
      ah[f] = *(const short8*)&As_h[ar * SP + lk * 8];
      al[f] = *(const short8*)&As_l[ar * SP + lk * 8];
      const int bc = wn * 64 + f * 16 + l15;
      bh[f] = *(const short8*)&Bs_h[bc * SP + lk * 8];
      bl[f] = *(const short8*)&Bs_l[bc * SP + lk * 8];
    }
#pragma unroll
    for (int mf = 0; mf < 4; ++mf)
#pragma unroll
      for (int nf = 0; nf < 4; ++nf) {
        acc[mf][nf] = __builtin_amdgcn_mfma_f32_16x16x32_bf16(
            ah[mf], bh[nf], acc[mf][nf], 0, 0, 0);
        acc[mf][nf] = __builtin_amdgcn_mfma_f32_16x16x32_bf16(
            ah[mf], bl[nf], acc[mf][nf], 0, 0, 0);
        acc[mf][nf] = __builtin_amdgcn_mfma_f32_16x16x32_bf16(
            al[mf], bh[nf], acc[mf][nf], 0, 0, 0);
      }
  }

  // Epilogue: D frag layout col=lane&15, row=(lane>>4)*4+i (m89-verified).
#pragma unroll
  for (int mf = 0; mf < 4; ++mf)
#pragma unroll
    for (int nf = 0; nf < 4; ++nf) {
      const int col = bn + wn * 64 + nf * 16 + l15;
      const int row0 = bm + wm * 64 + mf * 16 + lk * 4;
      const float bc = bias[col];
#pragma unroll
      for (int i = 0; i < 4; ++i)
        C[(size_t)(row0 + i) * N + col] = acc[mf][nf][i] + bc;
    }
}

// ---------------------------------------------------------------------------
// Per-(b,s,h) RMSNorm (q,k) + RoPE (q,k) + scatter to [B,H,S,64].
// One wave (64 lanes = head dim) per (b,s,h).
// ---------------------------------------------------------------------------
__global__ __launch_bounds__(256) void qkv_prep(
    const float* __restrict__ qkv, const float* __restrict__ q_scale,
    const float* __restrict__ k_scale, float* __restrict__ Qo,
    float* __restrict__ Ko, float* __restrict__ Vo) {
  const int lane = threadIdx.x & 63;
  const int gw = blockIdx.x * 4 + (threadIdx.x >> 6);  // global wave id
  const int h = gw & (CH - 1);
  const int s = (gw >> 4) & (CS - 1);
  const int b = gw >> 15;  // gw / (CH*CS)

  const size_t row = ((size_t)(b * CS + s)) * (3 * CDM) + (size_t)h * CHD + lane;
  float qv = qkv[row];
  float kv = qkv[row + CDM];
  const float vv = qkv[row + 2 * CDM];

  float sq = qv * qv, sk2 = kv * kv;
#pragma unroll
  for (int off = 32; off > 0; off >>= 1) {
    sq += __shfl_xor(sq, off);
    sk2 += __shfl_xor(sk2, off);
  }
  qv *= rsqrtf(sq * (1.f / CHD) + 1e-6f) * q_scale[lane];
  kv *= rsqrtf(sk2 * (1.f / CHD) + 1e-6f) * k_scale[lane];

  // RoPE: half-split rotary; angle index j = lane & 31, pos = s.
  const int j = lane & 31;
  const float inv = powf(10000.0f, -(float)j * (1.0f / 32.0f));
  const float ang = (float)s * inv;
  const float cs = cosf(ang);
  const float sn = sinf(ang);
  const float qp = __shfl_xor(qv, 32);
  const float kp = __shfl_xor(kv, 32);
  const float sgn = (lane < 32) ? -1.f : 1.f;
  const float qr = fmaf(qv, cs, sgn * qp * sn);
  const float kr = fmaf(kv, cs, sgn * kp * sn);

  const size_t ob = (((size_t)(b * CH + h)) * CS + s) * CHD + lane;
  Qo[ob] = qr;
  Ko[ob] = kr;
  Vo[ob] = vv;
}

// ---------------------------------------------------------------------------
// Flash-style frame-block-causal attention, v3 (dim-split lane pairs).
// (Unchanged this round; diagnosed LDS-instruction-throughput-bound:
// 16 ds_read_b128 x ~12cyc per wave-key = 192 LDS cyc vs 128 VALU cyc.
// Next structural step is MFMA QK^T/PV once GEMM validates the layout.)
// ---------------------------------------------------------------------------
__global__ __launch_bounds__(128) void attn_fwd(
    const float* __restrict__ Qm, const float* __restrict__ Km,
    const float* __restrict__ Vm, float* __restrict__ Om) {
  __shared__ float4 Ks4[64 * 16];  // 16 KB: 64 keys x 64 dims
  __shared__ float4 Vs4[64 * 16];  // 16 KB
  const int tid = threadIdx.x;
  const int qhalf = blockIdx.x & 1;            // which 64 queries of the frame
  const int f = (CNF - 1) - (blockIdx.x >> 1); // heavy frames launch first
  const int h = blockIdx.y;
  const int b = blockIdx.z;
  const int qi = qhalf * 64 + (tid >> 6) * 32 + (tid & 31);  // query in frame
  const int dh = (tid >> 5) & 1;                             // dim half 0/1
  const int s = f * CTPF + qi;
  const size_t hb = ((size_t)(b * CH + h)) * CS * CHD;

  // q: this lane's 32 dims of its query row.
  const float4* Qp = (const float4*)(Qm + hb + (size_t)s * CHD) + dh * 8;
  float4 q[8], o[8];
#pragma unroll
  for (int t = 0; t < 8; ++t) {
    q[t] = Qp[t];
    o[t] = make_float4(0.f, 0.f, 0.f, 0.f);
  }
  float m = -1e30f, l = 0.f;

  const int kf0 = (f == CNF - 1) ? 1 : 0;  // last-frame quirk: skip frame 0
  for (int kf = kf0; kf <= f; ++kf) {
    for (int half = 0; half < 2; ++half) {
      __syncthreads();  // protect LDS from previous chunk's readers
      const float4* Kg =
          (const float4*)(Km + hb + ((size_t)kf * CTPF + half * 64) * CHD);
      const float4* Vg =
          (const float4*)(Vm + hb + ((size_t)kf * CTPF + half * 64) * CHD);
#pragma unroll
      for (int i = 0; i < 8; ++i) {
        Ks4[i * 128 + tid] = Kg[i * 128 + tid];
        Vs4[i * 128 + tid] = Vg[i * 128 + tid];
      }
      __syncthreads();

      for (int j0 = 0; j0 < 64; j0 += 16) {
        float sc[16];
#pragma unroll
        for (int jj = 0; jj < 16; ++jj) {
          const float4* kr = &Ks4[(j0 + jj) * 16 + dh * 8];
          float d = 0.f;
#pragma unroll
          for (int t = 0; t < 8; ++t) {
            const float4 kv = kr[t];
            d = fmaf(q[t].x, kv.x, d);
            d = fmaf(q[t].y, kv.y, d);
            d = fmaf(q[t].z, kv.z, d);
            d = fmaf(q[t].w, kv.w, d);
          }
          // combine the two half-dim partial dots; both pair lanes get the sum
          d += __shfl_xor(d, 32);
          sc[jj] = d * 0.125f;  // HD^-0.5
        }
        float tm = sc[0];
#pragma unroll
        for (int jj = 1; jj < 16; ++jj) tm = fmaxf(tm, sc[jj]);
        if (tm > m) {  // defer-max: rescale only when the max actually grows
          const float c = __expf(m - tm);
          l *= c;
          m = tm;
#pragma unroll
          for (int t = 0; t < 8; ++t) {
            o[t].x *= c; o[t].y *= c; o[t].z *= c; o[t].w *= c;
          }
        }
#pragma unroll
        for (int jj = 0; jj < 16; ++jj) {
          const float p = __expf(sc[jj] - m);
          l += p;  // pair lanes accumulate identical l
          const float4* vr = &Vs4[(j0 + jj) * 16 + dh * 8];
#pragma unroll
          for (int t = 0; t < 8; ++t) {
            const float4 v = vr[t];
            o[t].x = fmaf(p, v.x, o[t].x);
            o[t].y = fmaf(p, v.y, o[t].y);
            o[t].z = fmaf(p, v.z, o[t].z);
            o[t].w = fmaf(p, v.w, o[t].w);
          }
        }
      }
    }
  }

  const float inv = 1.f / l;
  // Write this lane's 32 dims directly in [B,S,DM] layout.
  float4* Op =
      (float4*)(Om + ((size_t)(b * CS + s)) * CDM + (size_t)h * CHD) + dh * 8;
#pragma unroll
  for (int t = 0; t < 8; ++t) {
    float4 v = o[t];
    v.x *= inv; v.y *= inv; v.z *= inv; v.w *= inv;
    Op[t] = v;
  }
}

// ---------------------------------------------------------------------------
extern "C" void kernel_launch(void* const* d_in, const int* in_sizes, int n_in,
                              void* d_out, int out_size, void* d_ws, size_t ws_size,
                              hipStream_t stream) {
  const float* x       = (const float*)d_in[0];
  const float* Wqkv    = (const float*)d_in[1];
  const float* bqkv    = (const float*)d_in[2];
  const float* q_scale = (const float*)d_in[3];
  const float* k_scale = (const float*)d_in[4];
  const float* Wout    = (const float*)d_in[5];
  const float* bout    = (const float*)d_in[6];
  float* out = (float*)d_out;

  float* ws = (float*)d_ws;
  float* qkv = ws;                                   // [4096, 3072]
  float* Qb = ws + (size_t)(CB * CS) * (3 * CDM);    // [B,H,S,64] each
  float* Kb = Qb + (size_t)CB * CH * CS * CHD;
  float* Vb = Kb + (size_t)CB * CH * CS * CHD;
  float* AO = ws;  // attention output [B,S,DM]; aliases qkv (dead after prep)

  // 1) qkv = x @ Wqkv^T + bqkv  (split-bf16 MFMA)
  dim3 g1((3 * CDM) / 128, (CB * CS) / 128);
  gemm_bt_bias_mfma<<<g1, 256, 0, stream>>>(x, Wqkv, bqkv, qkv,
                                            CB * CS, 3 * CDM, CDM);

  // 2) RMSNorm + RoPE + scatter to [B,H,S,64]
  qkv_prep<<<(CB * CS * CH) / 4, 256, 0, stream>>>(qkv, q_scale, k_scale, Qb, Kb, Vb);

  // 3) frame-block-causal attention (two blocks per frame x head x batch)
  dim3 g3(CNF * 2, CH, CB);
  attn_fwd<<<g3, 128, 0, stream>>>(Qb, Kb, Vb, AO);

  // 4) out = AO @ Wout^T + bout  (split-bf16 MFMA)
  dim3 g4(CDM / 128, (CB * CS) / 128);
  gemm_bt_bias_mfma<<<g4, 256, 0, stream>>>(AO, Wout, bout, out,
                                            CB * CS, CDM, CDM);
}

// Round 8
// 348.169 us; speedup vs baseline: 29.2997x; 2.4092x over previous
//
#include <hip/hip_runtime.h>
#include <cstddef>
#include <cstdint>

// Problem constants (match reference)
constexpr int CB  = 2;     // batch
constexpr int CS  = 2048;  // seq len
constexpr int CDM = 1024;  // d_model
constexpr int CH  = 16;    // heads
constexpr int CHD = 64;    // head dim
constexpr int CTPF = 128;  // tokens per frame
constexpr int CNF = 16;    // frames

typedef __attribute__((ext_vector_type(8))) short short8;
typedef __attribute__((ext_vector_type(4))) float f32x4;

__device__ inline ushort f32_bf16_rne(float x) {
  uint32_t u = __float_as_uint(x);
  u += 0x7FFFu + ((u >> 16) & 1u);
  return (ushort)(u >> 16);
}
__device__ inline float bf16_f32(ushort h) {
  return __uint_as_float(((uint32_t)h) << 16);
}
// split 8 floats into hi/lo bf16 vectors
__device__ inline void split8(const float* v, short8& H, short8& L) {
#pragma unroll
  for (int j = 0; j < 8; ++j) {
    const ushort hh = f32_bf16_rne(v[j]);
    H[j] = (short)hh;
    L[j] = (short)f32_bf16_rne(v[j] - bf16_f32(hh));
  }
}

// ---------------------------------------------------------------------------
// GEMM: C[M,N] = A[M,K] @ B[N,K]^T + bias[N], split-bf16 MFMA (validated R7).
// ---------------------------------------------------------------------------
constexpr int SP = 40;  // LDS row stride in bf16 elements (32 + 8 pad)

__global__ __launch_bounds__(256) void gemm_bt_bias_mfma(
    const float* __restrict__ A, const float* __restrict__ Bm,
    const float* __restrict__ bias, float* __restrict__ C,
    int M, int N, int K) {
  __shared__ ushort As_h[128 * SP];
  __shared__ ushort As_l[128 * SP];
  __shared__ ushort Bs_h[128 * SP];
  __shared__ ushort Bs_l[128 * SP];
  const int tid = threadIdx.x;
  const int bm = blockIdx.y * 128;
  const int bn = blockIdx.x * 128;
  const int wid = tid >> 6;
  const int lane = tid & 63;
  const int wm = wid >> 1;
  const int wn = wid & 1;
  const int l15 = lane & 15;
  const int lk = lane >> 4;

  f32x4 acc[4][4];
#pragma unroll
  for (int i = 0; i < 4; ++i)
#pragma unroll
    for (int j = 0; j < 4; ++j) acc[i][j] = (f32x4){0.f, 0.f, 0.f, 0.f};

  for (int k0 = 0; k0 < K; k0 += 32) {
    __syncthreads();
#pragma unroll
    for (int c = 0; c < 2; ++c) {
      const int lin = tid + c * 256;
      const int row = lin >> 2;
      const int kq = (lin & 3) * 8;
      const float* ap = A + (size_t)(bm + row) * K + k0 + kq;
      const float4 a0 = *(const float4*)ap;
      const float4 a1 = *(const float4*)(ap + 4);
      const float va[8] = {a0.x, a0.y, a0.z, a0.w, a1.x, a1.y, a1.z, a1.w};
      short8 hv, lv;
      split8(va, hv, lv);
      *(short8*)&As_h[row * SP + kq] = hv;
      *(short8*)&As_l[row * SP + kq] = lv;
      const float* bp = Bm + (size_t)(bn + row) * K + k0 + kq;
      const float4 b0 = *(const float4*)bp;
      const float4 b1 = *(const float4*)(bp + 4);
      const float vb[8] = {b0.x, b0.y, b0.z, b0.w, b1.x, b1.y, b1.z, b1.w};
      split8(vb, hv, lv);
      *(short8*)&Bs_h[row * SP + kq] = hv;
      *(short8*)&Bs_l[row * SP + kq] = lv;
    }
    __syncthreads();

    short8 ah[4], al[4], bh[4], bl[4];
#pragma unroll
    for (int f = 0; f < 4; ++f) {
      const int ar = wm * 64 + f * 16 + l15;
      ah[f] = *(const short8*)&As_h[ar * SP + lk * 8];
      al[f] = *(const short8*)&As_l[ar * SP + lk * 8];
      const int bc = wn * 64 + f * 16 + l15;
      bh[f] = *(const short8*)&Bs_h[bc * SP + lk * 8];
      bl[f] = *(const short8*)&Bs_l[bc * SP + lk * 8];
    }
#pragma unroll
    for (int mf = 0; mf < 4; ++mf)
#pragma unroll
      for (int nf = 0; nf < 4; ++nf) {
        acc[mf][nf] = __builtin_amdgcn_mfma_f32_16x16x32_bf16(
            ah[mf], bh[nf], acc[mf][nf], 0, 0, 0);
        acc[mf][nf] = __builtin_amdgcn_mfma_f32_16x16x32_bf16(
            ah[mf], bl[nf], acc[mf][nf], 0, 0, 0);
        acc[mf][nf] = __builtin_amdgcn_mfma_f32_16x16x32_bf16(
            al[mf], bh[nf], acc[mf][nf], 0, 0, 0);
      }
  }

#pragma unroll
  for (int mf = 0; mf < 4; ++mf)
#pragma unroll
    for (int nf = 0; nf < 4; ++nf) {
      const int col = bn + wn * 64 + nf * 16 + l15;
      const int row0 = bm + wm * 64 + mf * 16 + lk * 4;
      const float bc = bias[col];
#pragma unroll
      for (int i = 0; i < 4; ++i)
        C[(size_t)(row0 + i) * N + col] = acc[mf][nf][i] + bc;
    }
}

// ---------------------------------------------------------------------------
// qkv_prep v2: RMSNorm + RoPE + scatter Q,K to [B,H,S,64] and V TRANSPOSED
// to Vt[B,H,64,S] (so attention's PV B-operand stages coalesced).
// Block = 64-token tile x head x batch; 4 waves x 16 tokens; lane = dim.
// ---------------------------------------------------------------------------
__global__ __launch_bounds__(256) void qkv_prep(
    const float* __restrict__ qkv, const float* __restrict__ q_scale,
    const float* __restrict__ k_scale, float* __restrict__ Qo,
    float* __restrict__ Ko, float* __restrict__ Vt) {
  __shared__ float Vtile[64][68];
  const int lane = threadIdx.x & 63;
  const int w = threadIdx.x >> 6;
  const int st = blockIdx.x;   // s-tile of 64
  const int h = blockIdx.y;
  const int b = blockIdx.z;

  const float qs = q_scale[lane];
  const float ks = k_scale[lane];
  const int j = lane & 31;
  const float inv = powf(10000.0f, -(float)j * (1.0f / 32.0f));
  const float sgn = (lane < 32) ? -1.f : 1.f;

  for (int it = 0; it < 16; ++it) {
    const int sl = w * 16 + it;
    const int s = st * 64 + sl;
    const size_t row =
        ((size_t)(b * CS + s)) * (3 * CDM) + (size_t)h * CHD + lane;
    float qv = qkv[row];
    float kv = qkv[row + CDM];
    const float vv = qkv[row + 2 * CDM];

    float sq = qv * qv, sk2 = kv * kv;
#pragma unroll
    for (int off = 32; off > 0; off >>= 1) {
      sq += __shfl_xor(sq, off);
      sk2 += __shfl_xor(sk2, off);
    }
    qv *= rsqrtf(sq * (1.f / CHD) + 1e-6f) * qs;
    kv *= rsqrtf(sk2 * (1.f / CHD) + 1e-6f) * ks;

    const float ang = (float)s * inv;
    const float cs = cosf(ang);
    const float sn = sinf(ang);
    const float qp = __shfl_xor(qv, 32);
    const float kp = __shfl_xor(kv, 32);
    const float qr = fmaf(qv, cs, sgn * qp * sn);
    const float kr = fmaf(kv, cs, sgn * kp * sn);

    const size_t ob = (((size_t)(b * CH + h)) * CS + s) * CHD + lane;
    Qo[ob] = qr;
    Ko[ob] = kr;
    Vtile[lane][sl] = vv;
  }
  __syncthreads();
  // write Vt[b,h,d, st*64 .. +63] coalesced
  const int d = threadIdx.x >> 2;
  const int sq4 = (threadIdx.x & 3) * 16;
  float* dst = Vt + (((size_t)(b * CH + h)) * CHD + d) * CS + st * 64 + sq4;
#pragma unroll
  for (int jj = 0; jj < 16; jj += 4)
    *(float4*)(dst + jj) = *(const float4*)&Vtile[d][sq4 + jj];
}

// ---------------------------------------------------------------------------
// attn_fwd_mfma: frame-block-causal flash attention on matrix cores.
// Block = (frame f, head, batch), 256 thr = 4 waves x 32 queries.
// Swapped QK^T: mfma(A=K, B=Q) -> S^T frags: lane's query = l15 (fixed),
// keys = rows -> softmax is in-lane (16 vals) + shfl_xor(16,32). P split to
// bf16 h/l in wave-private LDS rows; PV: mfma(A=P, B=Vt). All matmuls use
// the 3-term split (h*h + h*l + l*h) -> fp32-grade, absmax unchanged.
// LDS 73.7 KB -> 2 blocks/CU (8 waves/CU). Mask: frame f attends frames
// [0..f], except f==15 skips frame 0 (reference quirk; exact since exp->0).
// ---------------------------------------------------------------------------
constexpr int SP2 = 72;  // LDS row stride (64 + 8 pad), 144 B

__global__ __launch_bounds__(256, 2) void attn_fwd_mfma(
    const float* __restrict__ Qm, const float* __restrict__ Km,
    const float* __restrict__ Vt, float* __restrict__ Om) {
  __shared__ ushort Ks_h[64 * SP2], Ks_l[64 * SP2];   // K chunk [key][d]
  __shared__ ushort Vs_h[64 * SP2], Vs_l[64 * SP2];   // V^T chunk [d][key]
  __shared__ ushort Ps_h[128 * SP2], Ps_l[128 * SP2]; // P [q][key], wave-priv
  const int tid = threadIdx.x;
  const int f = (CNF - 1) - blockIdx.x;  // heavy frames first
  const int h = blockIdx.y;
  const int b = blockIdx.z;
  const int lane = tid & 63;
  const int wid = tid >> 6;
  const int l15 = lane & 15;
  const int lk = lane >> 4;
  const int qb = wid * 32;  // wave's queries within the frame
  const size_t hb = ((size_t)(b * CH + h)) * CS * CHD;   // Q/K [b,h,s,d]
  const size_t vtb = ((size_t)(b * CH + h)) * CHD * CS;  // Vt [b,h,d,s]

  // Q B-frags in registers (pre-scaled by HD^-0.5), split h/l.
  short8 qh[2][2], ql[2][2];
#pragma unroll
  for (int nf = 0; nf < 2; ++nf)
#pragma unroll
    for (int ks = 0; ks < 2; ++ks) {
      const float* qp = Qm + hb +
          (size_t)(f * CTPF + qb + nf * 16 + l15) * CHD + ks * 32 + lk * 8;
      const float4 x0 = *(const float4*)qp;
      const float4 x1 = *(const float4*)(qp + 4);
      float v[8] = {x0.x, x0.y, x0.z, x0.w, x1.x, x1.y, x1.z, x1.w};
#pragma unroll
      for (int jj = 0; jj < 8; ++jj) v[jj] *= 0.125f;
      split8(v, qh[nf][ks], ql[nf][ks]);
    }

  f32x4 accO[2][4];
#pragma unroll
  for (int mo = 0; mo < 2; ++mo)
#pragma unroll
    for (int no = 0; no < 4; ++no) accO[mo][no] = (f32x4){0.f, 0.f, 0.f, 0.f};
  float m[2] = {-1e30f, -1e30f};
  float lsum[2] = {0.f, 0.f};

  const int kf0 = (f == CNF - 1) ? 1 : 0;  // last-frame quirk
  for (int kf = kf0; kf <= f; ++kf) {
#pragma unroll 1
    for (int half = 0; half < 2; ++half) {
      const int cb = kf * CTPF + half * 64;  // chunk base key
      __syncthreads();  // prev chunk's K/V readers done
      {
        const int r = tid >> 2;            // 0..63
        const int cq = (tid & 3) * 16;     // 0,16,32,48
        // K: rows = key, cols = d
        const float* kp = Km + hb + (size_t)(cb + r) * CHD + cq;
        float kv8[8];
        short8 H, L;
        *(float4*)&kv8[0] = *(const float4*)kp;
        *(float4*)&kv8[4] = *(const float4*)(kp + 4);
        split8(kv8, H, L);
        *(short8*)&Ks_h[r * SP2 + cq] = H;
        *(short8*)&Ks_l[r * SP2 + cq] = L;
        *(float4*)&kv8[0] = *(const float4*)(kp + 8);
        *(float4*)&kv8[4] = *(const float4*)(kp + 12);
        split8(kv8, H, L);
        *(short8*)&Ks_h[r * SP2 + cq + 8] = H;
        *(short8*)&Ks_l[r * SP2 + cq + 8] = L;
        // V^T: rows = d, cols = key
        const float* vp = Vt + vtb + (size_t)r * CS + cb + cq;
        *(float4*)&kv8[0] = *(const float4*)vp;
        *(float4*)&kv8[4] = *(const float4*)(vp + 4);
        split8(kv8, H, L);
        *(short8*)&Vs_h[r * SP2 + cq] = H;
        *(short8*)&Vs_l[r * SP2 + cq] = L;
        *(float4*)&kv8[0] = *(const float4*)(vp + 8);
        *(float4*)&kv8[4] = *(const float4*)(vp + 12);
        split8(kv8, H, L);
        *(short8*)&Vs_h[r * SP2 + cq + 8] = H;
        *(short8*)&Vs_l[r * SP2 + cq + 8] = L;
      }
      __syncthreads();

      // QK^T swapped: S^T[key][q]; acc frags [mf=key/16][nf=q/16]
      f32x4 sacc[4][2];
#pragma unroll
      for (int mf = 0; mf < 4; ++mf)
#pragma unroll
        for (int nf = 0; nf < 2; ++nf) sacc[mf][nf] = (f32x4){0.f, 0.f, 0.f, 0.f};
#pragma unroll
      for (int ks = 0; ks < 2; ++ks) {
        short8 kh[4], kl[4];
#pragma unroll
        for (int mf = 0; mf < 4; ++mf) {
          const int base = (mf * 16 + l15) * SP2 + ks * 32 + lk * 8;
          kh[mf] = *(const short8*)&Ks_h[base];
          kl[mf] = *(const short8*)&Ks_l[base];
        }
#pragma unroll
        for (int mf = 0; mf < 4; ++mf)
#pragma unroll
          for (int nf = 0; nf < 2; ++nf) {
            sacc[mf][nf] = __builtin_amdgcn_mfma_f32_16x16x32_bf16(
                kh[mf], qh[nf][ks], sacc[mf][nf], 0, 0, 0);
            sacc[mf][nf] = __builtin_amdgcn_mfma_f32_16x16x32_bf16(
                kh[mf], ql[nf][ks], sacc[mf][nf], 0, 0, 0);
            sacc[mf][nf] = __builtin_amdgcn_mfma_f32_16x16x32_bf16(
                kl[mf], qh[nf][ks], sacc[mf][nf], 0, 0, 0);
          }
      }

      // online softmax per query column (nf): in-lane 16 keys + lk reduce
      float c[2];
#pragma unroll
      for (int nf = 0; nf < 2; ++nf) {
        float cm = sacc[0][nf][0];
#pragma unroll
        for (int mf = 0; mf < 4; ++mf)
#pragma unroll
          for (int i = 0; i < 4; ++i) cm = fmaxf(cm, sacc[mf][nf][i]);
        cm = fmaxf(cm, __shfl_xor(cm, 16));
        cm = fmaxf(cm, __shfl_xor(cm, 32));
        const float mn = fmaxf(m[nf], cm);
        c[nf] = __expf(m[nf] - mn);
        m[nf] = mn;
        float ps = 0.f;
        const int qrow = qb + nf * 16 + l15;
#pragma unroll
        for (int mf = 0; mf < 4; ++mf) {
          float p0 = __expf(sacc[mf][nf][0] - mn);
          float p1 = __expf(sacc[mf][nf][1] - mn);
          float p2 = __expf(sacc[mf][nf][2] - mn);
          float p3 = __expf(sacc[mf][nf][3] - mn);
          ps += (p0 + p1) + (p2 + p3);
          const ushort h0 = f32_bf16_rne(p0), h1 = f32_bf16_rne(p1);
          const ushort h2 = f32_bf16_rne(p2), h3 = f32_bf16_rne(p3);
          uint2 hw, lw;
          hw.x = (uint32_t)h0 | ((uint32_t)h1 << 16);
          hw.y = (uint32_t)h2 | ((uint32_t)h3 << 16);
          lw.x = (uint32_t)f32_bf16_rne(p0 - bf16_f32(h0)) |
                 ((uint32_t)f32_bf16_rne(p1 - bf16_f32(h1)) << 16);
          lw.y = (uint32_t)f32_bf16_rne(p2 - bf16_f32(h2)) |
                 ((uint32_t)f32_bf16_rne(p3 - bf16_f32(h3)) << 16);
          const int off = qrow * SP2 + mf * 16 + lk * 4;
          *(uint2*)&Ps_h[off] = hw;
          *(uint2*)&Ps_l[off] = lw;
        }
        ps += __shfl_xor(ps, 16);
        ps += __shfl_xor(ps, 32);
        lsum[nf] = lsum[nf] * c[nf] + ps;
      }
      // rescale O accumulator (O rows q = mo*16 + lk*4 + i need c from lane
      // l15' = lk*4+i, frag index nf = mo)
#pragma unroll
      for (int mo = 0; mo < 2; ++mo)
#pragma unroll
        for (int i = 0; i < 4; ++i) {
          const float cq = __shfl(c[mo], lk * 4 + i);
#pragma unroll
          for (int no = 0; no < 4; ++no) accO[mo][no][i] *= cq;
        }

      // PV: O[q][d] += P[q][key] * Vt[d][key]
#pragma unroll
      for (int ks = 0; ks < 2; ++ks) {
        short8 pa_h[2], pa_l[2], vb_h[4], vb_l[4];
#pragma unroll
        for (int mo = 0; mo < 2; ++mo) {
          const int base = (qb + mo * 16 + l15) * SP2 + ks * 32 + lk * 8;
          pa_h[mo] = *(const short8*)&Ps_h[base];
          pa_l[mo] = *(const short8*)&Ps_l[base];
        }
#pragma unroll
        for (int no = 0; no < 4; ++no) {
          const int base = (no * 16 + l15) * SP2 + ks * 32 + lk * 8;
          vb_h[no] = *(const short8*)&Vs_h[base];
          vb_l[no] = *(const short8*)&Vs_l[base];
        }
#pragma unroll
        for (int mo = 0; mo < 2; ++mo)
#pragma unroll
          for (int no = 0; no < 4; ++no) {
            accO[mo][no] = __builtin_amdgcn_mfma_f32_16x16x32_bf16(
                pa_h[mo], vb_h[no], accO[mo][no], 0, 0, 0);
            accO[mo][no] = __builtin_amdgcn_mfma_f32_16x16x32_bf16(
                pa_h[mo], vb_l[no], accO[mo][no], 0, 0, 0);
            accO[mo][no] = __builtin_amdgcn_mfma_f32_16x16x32_bf16(
                pa_l[mo], vb_h[no], accO[mo][no], 0, 0, 0);
          }
      }
    }
  }

  // normalize and write O in [B,S,DM] layout
  const float il0 = 1.f / lsum[0];
  const float il1 = 1.f / lsum[1];
#pragma unroll
  for (int mo = 0; mo < 2; ++mo) {
    const float myil = (mo == 0) ? il0 : il1;
#pragma unroll
    for (int i = 0; i < 4; ++i) {
      const float wv = __shfl(myil, lk * 4 + i);
      const int srow = f * CTPF + qb + mo * 16 + lk * 4 + i;
      float* orow = Om + (size_t)(b * CS + srow) * CDM + h * CHD;
#pragma unroll
      for (int no = 0; no < 4; ++no)
        orow[no * 16 + l15] = accO[mo][no][i] * wv;
    }
  }
}

// ---------------------------------------------------------------------------
extern "C" void kernel_launch(void* const* d_in, const int* in_sizes, int n_in,
                              void* d_out, int out_size, void* d_ws, size_t ws_size,
                              hipStream_t stream) {
  const float* x       = (const float*)d_in[0];
  const float* Wqkv    = (const float*)d_in[1];
  const float* bqkv    = (const float*)d_in[2];
  const float* q_scale = (const float*)d_in[3];
  const float* k_scale = (const float*)d_in[4];
  const float* Wout    = (const float*)d_in[5];
  const float* bout    = (const float*)d_in[6];
  float* out = (float*)d_out;

  float* ws = (float*)d_ws;
  float* qkv = ws;                                   // [4096, 3072]
  float* Qb = ws + (size_t)(CB * CS) * (3 * CDM);    // [B,H,S,64]
  float* Kb = Qb + (size_t)CB * CH * CS * CHD;       // [B,H,S,64]
  float* Vtb = Kb + (size_t)CB * CH * CS * CHD;      // [B,H,64,S] (transposed)
  float* AO = ws;  // attention output [B,S,DM]; aliases qkv (dead after prep)

  // 1) qkv = x @ Wqkv^T + bqkv  (split-bf16 MFMA)
  dim3 g1((3 * CDM) / 128, (CB * CS) / 128);
  gemm_bt_bias_mfma<<<g1, 256, 0, stream>>>(x, Wqkv, bqkv, qkv,
                                            CB * CS, 3 * CDM, CDM);

  // 2) RMSNorm + RoPE; Q,K -> [B,H,S,64], V -> transposed [B,H,64,S]
  dim3 g2(CS / 64, CH, CB);
  qkv_prep<<<g2, 256, 0, stream>>>(qkv, q_scale, k_scale, Qb, Kb, Vtb);

  // 3) frame-block-causal attention on MFMA
  dim3 g3(CNF, CH, CB);
  attn_fwd_mfma<<<g3, 256, 0, stream>>>(Qb, Kb, Vtb, AO);

  // 4) out = AO @ Wout^T + bout  (split-bf16 MFMA)
  dim3 g4(CDM / 128, (CB * CS) / 128);
  gemm_bt_bias_mfma<<<g4, 256, 0, stream>>>(AO, Wout, bout, out,
                                            CB * CS, CDM, CDM);
}

// Round 9
// 316.424 us; speedup vs baseline: 32.2391x; 1.1003x over previous
//
#include <hip/hip_runtime.h>
#include <cstddef>
#include <cstdint>

// Problem constants (match reference)
constexpr int CB  = 2;     // batch
constexpr int CS  = 2048;  // seq len
constexpr int CDM = 1024;  // d_model
constexpr int CH  = 16;    // heads
constexpr int CHD = 64;    // head dim
constexpr int CTPF = 128;  // tokens per frame
constexpr int CNF = 16;    // frames

typedef __attribute__((ext_vector_type(8))) short short8;
typedef __attribute__((ext_vector_type(4))) float f32x4;

__device__ inline ushort f32_bf16_rne(float x) {
  uint32_t u = __float_as_uint(x);
  u += 0x7FFFu + ((u >> 16) & 1u);
  return (ushort)(u >> 16);
}
__device__ inline float bf16_f32(ushort h) {
  return __uint_as_float(((uint32_t)h) << 16);
}
// split 8 floats into hi/lo bf16 vectors
__device__ inline void split8(const float* v, short8& H, short8& L) {
#pragma unroll
  for (int j = 0; j < 8; ++j) {
    const ushort hh = f32_bf16_rne(v[j]);
    H[j] = (short)hh;
    L[j] = (short)f32_bf16_rne(v[j] - bf16_f32(hh));
  }
}

// ---------------------------------------------------------------------------
// GEMM: C[M,N] = A[M,K] @ B[N,K]^T + bias[N], split-bf16 MFMA (validated R7).
// ---------------------------------------------------------------------------
constexpr int SP = 40;  // LDS row stride in bf16 elements (32 + 8 pad)

__global__ __launch_bounds__(256) void gemm_bt_bias_mfma(
    const float* __restrict__ A, const float* __restrict__ Bm,
    const float* __restrict__ bias, float* __restrict__ C,
    int M, int N, int K) {
  __shared__ ushort As_h[128 * SP];
  __shared__ ushort As_l[128 * SP];
  __shared__ ushort Bs_h[128 * SP];
  __shared__ ushort Bs_l[128 * SP];
  const int tid = threadIdx.x;
  const int bm = blockIdx.y * 128;
  const int bn = blockIdx.x * 128;
  const int wid = tid >> 6;
  const int lane = tid & 63;
  const int wm = wid >> 1;
  const int wn = wid & 1;
  const int l15 = lane & 15;
  const int lk = lane >> 4;

  f32x4 acc[4][4];
#pragma unroll
  for (int i = 0; i < 4; ++i)
#pragma unroll
    for (int j = 0; j < 4; ++j) acc[i][j] = (f32x4){0.f, 0.f, 0.f, 0.f};

  for (int k0 = 0; k0 < K; k0 += 32) {
    __syncthreads();
#pragma unroll
    for (int c = 0; c < 2; ++c) {
      const int lin = tid + c * 256;
      const int row = lin >> 2;
      const int kq = (lin & 3) * 8;
      const float* ap = A + (size_t)(bm + row) * K + k0 + kq;
      const float4 a0 = *(const float4*)ap;
      const float4 a1 = *(const float4*)(ap + 4);
      const float va[8] = {a0.x, a0.y, a0.z, a0.w, a1.x, a1.y, a1.z, a1.w};
      short8 hv, lv;
      split8(va, hv, lv);
      *(short8*)&As_h[row * SP + kq] = hv;
      *(short8*)&As_l[row * SP + kq] = lv;
      const float* bp = Bm + (size_t)(bn + row) * K + k0 + kq;
      const float4 b0 = *(const float4*)bp;
      const float4 b1 = *(const float4*)(bp + 4);
      const float vb[8] = {b0.x, b0.y, b0.z, b0.w, b1.x, b1.y, b1.z, b1.w};
      split8(vb, hv, lv);
      *(short8*)&Bs_h[row * SP + kq] = hv;
      *(short8*)&Bs_l[row * SP + kq] = lv;
    }
    __syncthreads();

    short8 ah[4], al[4], bh[4], bl[4];
#pragma unroll
    for (int f = 0; f < 4; ++f) {
      const int ar = wm * 64 + f * 16 + l15;
      ah[f] = *(const short8*)&As_h[ar * SP + lk * 8];
      al[f] = *(const short8*)&As_l[ar * SP + lk * 8];
      const int bc = wn * 64 + f * 16 + l15;
      bh[f] = *(const short8*)&Bs_h[bc * SP + lk * 8];
      bl[f] = *(const short8*)&Bs_l[bc * SP + lk * 8];
    }
#pragma unroll
    for (int mf = 0; mf < 4; ++mf)
#pragma unroll
      for (int nf = 0; nf < 4; ++nf) {
        acc[mf][nf] = __builtin_amdgcn_mfma_f32_16x16x32_bf16(
            ah[mf], bh[nf], acc[mf][nf], 0, 0, 0);
        acc[mf][nf] = __builtin_amdgcn_mfma_f32_16x16x32_bf16(
            ah[mf], bl[nf], acc[mf][nf], 0, 0, 0);
        acc[mf][nf] = __builtin_amdgcn_mfma_f32_16x16x32_bf16(
            al[mf], bh[nf], acc[mf][nf], 0, 0, 0);
      }
  }

#pragma unroll
  for (int mf = 0; mf < 4; ++mf)
#pragma unroll
    for (int nf = 0; nf < 4; ++nf) {
      const int col = bn + wn * 64 + nf * 16 + l15;
      const int row0 = bm + wm * 64 + mf * 16 + lk * 4;
      const float bc = bias[col];
#pragma unroll
      for (int i = 0; i < 4; ++i)
        C[(size_t)(row0 + i) * N + col] = acc[mf][nf][i] + bc;
    }
}

// ---------------------------------------------------------------------------
// qkv_prep v3: RMSNorm + RoPE, then PRE-SPLIT everything to bf16 h/l:
//   Qh/Ql [B,H,S,64]  (pre-scaled by HD^-0.5)
//   Kh/Kl [B,H,S,64]
//   Vth/Vtl [B,H,64,S] (transposed for PV's B-operand)
// Same rne split values the attention kernel computed per-chunk in R8 —
// numerics identical, but the split VALU runs ONCE instead of per-restage.
// ---------------------------------------------------------------------------
__global__ __launch_bounds__(256) void qkv_prep(
    const float* __restrict__ qkv, const float* __restrict__ q_scale,
    const float* __restrict__ k_scale,
    ushort* __restrict__ Qh, ushort* __restrict__ Ql,
    ushort* __restrict__ Kh, ushort* __restrict__ Kl,
    ushort* __restrict__ Vth, ushort* __restrict__ Vtl) {
  __shared__ float Vtile[64][68];
  const int lane = threadIdx.x & 63;
  const int w = threadIdx.x >> 6;
  const int st = blockIdx.x;   // s-tile of 64
  const int h = blockIdx.y;
  const int b = blockIdx.z;

  const float qs = q_scale[lane];
  const float ks = k_scale[lane];
  const int j = lane & 31;
  const float inv = powf(10000.0f, -(float)j * (1.0f / 32.0f));
  const float sgn = (lane < 32) ? -1.f : 1.f;

  for (int it = 0; it < 16; ++it) {
    const int sl = w * 16 + it;
    const int s = st * 64 + sl;
    const size_t row =
        ((size_t)(b * CS + s)) * (3 * CDM) + (size_t)h * CHD + lane;
    float qv = qkv[row];
    float kv = qkv[row + CDM];
    const float vv = qkv[row + 2 * CDM];

    float sq = qv * qv, sk2 = kv * kv;
#pragma unroll
    for (int off = 32; off > 0; off >>= 1) {
      sq += __shfl_xor(sq, off);
      sk2 += __shfl_xor(sk2, off);
    }
    qv *= rsqrtf(sq * (1.f / CHD) + 1e-6f) * qs;
    kv *= rsqrtf(sk2 * (1.f / CHD) + 1e-6f) * ks;

    const float ang = (float)s * inv;
    const float cs = cosf(ang);
    const float sn = sinf(ang);
    const float qp = __shfl_xor(qv, 32);
    const float kp = __shfl_xor(kv, 32);
    const float qr = fmaf(qv, cs, sgn * qp * sn) * 0.125f;  // pre-scale Q
    const float kr = fmaf(kv, cs, sgn * kp * sn);

    const size_t ob = (((size_t)(b * CH + h)) * CS + s) * CHD + lane;
    const ushort qhh = f32_bf16_rne(qr);
    Qh[ob] = qhh;
    Ql[ob] = f32_bf16_rne(qr - bf16_f32(qhh));
    const ushort khh = f32_bf16_rne(kr);
    Kh[ob] = khh;
    Kl[ob] = f32_bf16_rne(kr - bf16_f32(khh));
    Vtile[lane][sl] = vv;
  }
  __syncthreads();
  // write Vt[b,h,d, st*64 .. +63] split h/l, coalesced
  const int d = threadIdx.x >> 2;
  const int sq4 = (threadIdx.x & 3) * 16;
  const size_t vb = (((size_t)(b * CH + h)) * CHD + d) * CS + st * 64 + sq4;
#pragma unroll
  for (int j0 = 0; j0 < 16; j0 += 8) {
    float v8[8];
#pragma unroll
    for (int jj = 0; jj < 8; ++jj) v8[jj] = Vtile[d][sq4 + j0 + jj];
    short8 H, L;
    split8(v8, H, L);
    *(short8*)&Vth[vb + j0] = H;
    *(short8*)&Vtl[vb + j0] = L;
  }
}

// ---------------------------------------------------------------------------
// attn_fwd_mfma v2: same structure as R8 (swapped QK^T, wave-private P,
// 3-term split everywhere) with two mechanical changes:
//  - operands arrive PRE-SPLIT (staging = pure 16B copies, no VALU split)
//  - LDS stride 72 -> 64 + XOR swizzle (ushort idx ^= (row&7)<<3), applied
//    on both write and read: kills the 4-bank-stride conflicts (7.7M cyc).
// LDS 64 KB -> 2 blocks/CU. Mask: frame f attends frames [0..f], except
// f==15 skips frame 0 (reference quirk; exact since exp underflows to 0).
// ---------------------------------------------------------------------------
__global__ __launch_bounds__(256, 2) void attn_fwd_mfma(
    const ushort* __restrict__ Qh, const ushort* __restrict__ Ql,
    const ushort* __restrict__ Kh, const ushort* __restrict__ Kl,
    const ushort* __restrict__ Vth, const ushort* __restrict__ Vtl,
    float* __restrict__ Om) {
  __shared__ ushort Ks_h[64 * 64], Ks_l[64 * 64];   // K chunk [key][d]
  __shared__ ushort Vs_h[64 * 64], Vs_l[64 * 64];   // V^T chunk [d][key]
  __shared__ ushort Ps_h[128 * 64], Ps_l[128 * 64]; // P [q][key], wave-priv
  const int tid = threadIdx.x;
  const int f = (CNF - 1) - blockIdx.x;  // heavy frames first
  const int h = blockIdx.y;
  const int b = blockIdx.z;
  const int lane = tid & 63;
  const int wid = tid >> 6;
  const int l15 = lane & 15;
  const int lk = lane >> 4;
  const int qb = wid * 32;  // wave's queries within the frame
  const size_t hb = ((size_t)(b * CH + h)) * CS * CHD;   // Q/K [b,h,s,d]
  const size_t vtb = ((size_t)(b * CH + h)) * CHD * CS;  // Vt [b,h,d,s]

  // Q B-frags straight from pre-split global (already scaled by HD^-0.5).
  short8 qh[2][2], ql[2][2];
#pragma unroll
  for (int nf = 0; nf < 2; ++nf)
#pragma unroll
    for (int ks = 0; ks < 2; ++ks) {
      const size_t qoff = hb +
          (size_t)(f * CTPF + qb + nf * 16 + l15) * CHD + ks * 32 + lk * 8;
      qh[nf][ks] = *(const short8*)(Qh + qoff);
      ql[nf][ks] = *(const short8*)(Ql + qoff);
    }

  f32x4 accO[2][4];
#pragma unroll
  for (int mo = 0; mo < 2; ++mo)
#pragma unroll
    for (int no = 0; no < 4; ++no) accO[mo][no] = (f32x4){0.f, 0.f, 0.f, 0.f};
  float m[2] = {-1e30f, -1e30f};
  float lsum[2] = {0.f, 0.f};

  const int kf0 = (f == CNF - 1) ? 1 : 0;  // last-frame quirk
  for (int kf = kf0; kf <= f; ++kf) {
#pragma unroll 1
    for (int half = 0; half < 2; ++half) {
      const int cb = kf * CTPF + half * 64;  // chunk base key
      __syncthreads();  // prev chunk's K/V readers done
      {
        const int r = tid >> 2;            // 0..63
        const int cq = (tid & 3) * 16;     // 0,16,32,48
        const int mk = (r & 7) << 3;       // XOR swizzle (ushort units)
        // K: rows = key, cols = d
        const size_t ko = hb + (size_t)(cb + r) * CHD + cq;
        *(short8*)&Ks_h[r * 64 + (cq ^ mk)] = *(const short8*)(Kh + ko);
        *(short8*)&Ks_h[r * 64 + ((cq + 8) ^ mk)] = *(const short8*)(Kh + ko + 8);
        *(short8*)&Ks_l[r * 64 + (cq ^ mk)] = *(const short8*)(Kl + ko);
        *(short8*)&Ks_l[r * 64 + ((cq + 8) ^ mk)] = *(const short8*)(Kl + ko + 8);
        // V^T: rows = d, cols = key
        const size_t vo = vtb + (size_t)r * CS + cb + cq;
        *(short8*)&Vs_h[r * 64 + (cq ^ mk)] = *(const short8*)(Vth + vo);
        *(short8*)&Vs_h[r * 64 + ((cq + 8) ^ mk)] = *(const short8*)(Vth + vo + 8);
        *(short8*)&Vs_l[r * 64 + (cq ^ mk)] = *(const short8*)(Vtl + vo);
        *(short8*)&Vs_l[r * 64 + ((cq + 8) ^ mk)] = *(const short8*)(Vtl + vo + 8);
      }
      __syncthreads();

      // QK^T swapped: S^T[key][q]; acc frags [mf=key/16][nf=q/16]
      f32x4 sacc[4][2];
#pragma unroll
      for (int mf = 0; mf < 4; ++mf)
#pragma unroll
        for (int nf = 0; nf < 2; ++nf) sacc[mf][nf] = (f32x4){0.f, 0.f, 0.f, 0.f};
#pragma unroll
      for (int ks = 0; ks < 2; ++ks) {
        short8 kh[4], kl[4];
#pragma unroll
        for (int mf = 0; mf < 4; ++mf) {
          const int krow = mf * 16 + l15;
          const int base = krow * 64 + ((ks * 32 + lk * 8) ^ ((krow & 7) << 3));
          kh[mf] = *(const short8*)&Ks_h[base];
          kl[mf] = *(const short8*)&Ks_l[base];
        }
#pragma unroll
        for (int mf = 0; mf < 4; ++mf)
#pragma unroll
          for (int nf = 0; nf < 2; ++nf) {
            sacc[mf][nf] = __builtin_amdgcn_mfma_f32_16x16x32_bf16(
                kh[mf], qh[nf][ks], sacc[mf][nf], 0, 0, 0);
            sacc[mf][nf] = __builtin_amdgcn_mfma_f32_16x16x32_bf16(
                kh[mf], ql[nf][ks], sacc[mf][nf], 0, 0, 0);
            sacc[mf][nf] = __builtin_amdgcn_mfma_f32_16x16x32_bf16(
                kl[mf], qh[nf][ks], sacc[mf][nf], 0, 0, 0);
          }
      }

      // online softmax per query column (nf): in-lane 16 keys + lk reduce
      float c[2];
#pragma unroll
      for (int nf = 0; nf < 2; ++nf) {
        float cm = sacc[0][nf][0];
#pragma unroll
        for (int mf = 0; mf < 4; ++mf)
#pragma unroll
          for (int i = 0; i < 4; ++i) cm = fmaxf(cm, sacc[mf][nf][i]);
        cm = fmaxf(cm, __shfl_xor(cm, 16));
        cm = fmaxf(cm, __shfl_xor(cm, 32));
        const float mn = fmaxf(m[nf], cm);
        c[nf] = __expf(m[nf] - mn);
        m[nf] = mn;
        float ps = 0.f;
        const int qrow = qb + nf * 16 + l15;
        const int qmk = (qrow & 7) << 3;
#pragma unroll
        for (int mf = 0; mf < 4; ++mf) {
          float p0 = __expf(sacc[mf][nf][0] - mn);
          float p1 = __expf(sacc[mf][nf][1] - mn);
          float p2 = __expf(sacc[mf][nf][2] - mn);
          float p3 = __expf(sacc[mf][nf][3] - mn);
          ps += (p0 + p1) + (p2 + p3);
          const ushort h0 = f32_bf16_rne(p0), h1 = f32_bf16_rne(p1);
          const ushort h2 = f32_bf16_rne(p2), h3 = f32_bf16_rne(p3);
          uint2 hw, lw;
          hw.x = (uint32_t)h0 | ((uint32_t)h1 << 16);
          hw.y = (uint32_t)h2 | ((uint32_t)h3 << 16);
          lw.x = (uint32_t)f32_bf16_rne(p0 - bf16_f32(h0)) |
                 ((uint32_t)f32_bf16_rne(p1 - bf16_f32(h1)) << 16);
          lw.y = (uint32_t)f32_bf16_rne(p2 - bf16_f32(h2)) |
                 ((uint32_t)f32_bf16_rne(p3 - bf16_f32(h3)) << 16);
          const int off = qrow * 64 + ((mf * 16 + lk * 4) ^ qmk);
          *(uint2*)&Ps_h[off] = hw;
          *(uint2*)&Ps_l[off] = lw;
        }
        ps += __shfl_xor(ps, 16);
        ps += __shfl_xor(ps, 32);
        lsum[nf] = lsum[nf] * c[nf] + ps;
      }
      // rescale O accumulator
#pragma unroll
      for (int mo = 0; mo < 2; ++mo)
#pragma unroll
        for (int i = 0; i < 4; ++i) {
          const float cq = __shfl(c[mo], lk * 4 + i);
#pragma unroll
          for (int no = 0; no < 4; ++no) accO[mo][no][i] *= cq;
        }

      // PV: O[q][d] += P[q][key] * Vt[d][key]
#pragma unroll
      for (int ks = 0; ks < 2; ++ks) {
        short8 pa_h[2], pa_l[2], vb_h[4], vb_l[4];
#pragma unroll
        for (int mo = 0; mo < 2; ++mo) {
          const int qrow = qb + mo * 16 + l15;
          const int base = qrow * 64 + ((ks * 32 + lk * 8) ^ ((qrow & 7) << 3));
          pa_h[mo] = *(const short8*)&Ps_h[base];
          pa_l[mo] = *(const short8*)&Ps_l[base];
        }
#pragma unroll
        for (int no = 0; no < 4; ++no) {
          const int vrow = no * 16 + l15;
          const int base = vrow * 64 + ((ks * 32 + lk * 8) ^ ((vrow & 7) << 3));
          vb_h[no] = *(const short8*)&Vs_h[base];
          vb_l[no] = *(const short8*)&Vs_l[base];
        }
#pragma unroll
        for (int mo = 0; mo < 2; ++mo)
#pragma unroll
          for (int no = 0; no < 4; ++no) {
            accO[mo][no] = __builtin_amdgcn_mfma_f32_16x16x32_bf16(
                pa_h[mo], vb_h[no], accO[mo][no], 0, 0, 0);
            accO[mo][no] = __builtin_amdgcn_mfma_f32_16x16x32_bf16(
                pa_h[mo], vb_l[no], accO[mo][no], 0, 0, 0);
            accO[mo][no] = __builtin_amdgcn_mfma_f32_16x16x32_bf16(
                pa_l[mo], vb_h[no], accO[mo][no], 0, 0, 0);
          }
      }
    }
  }

  // normalize and write O in [B,S,DM] layout
  const float il0 = 1.f / lsum[0];
  const float il1 = 1.f / lsum[1];
#pragma unroll
  for (int mo = 0; mo < 2; ++mo) {
    const float myil = (mo == 0) ? il0 : il1;
#pragma unroll
    for (int i = 0; i < 4; ++i) {
      const float wv = __shfl(myil, lk * 4 + i);
      const int srow = f * CTPF + qb + mo * 16 + lk * 4 + i;
      float* orow = Om + (size_t)(b * CS + srow) * CDM + h * CHD;
#pragma unroll
      for (int no = 0; no < 4; ++no)
        orow[no * 16 + l15] = accO[mo][no][i] * wv;
    }
  }
}

// ---------------------------------------------------------------------------
extern "C" void kernel_launch(void* const* d_in, const int* in_sizes, int n_in,
                              void* d_out, int out_size, void* d_ws, size_t ws_size,
                              hipStream_t stream) {
  const float* x       = (const float*)d_in[0];
  const float* Wqkv    = (const float*)d_in[1];
  const float* bqkv    = (const float*)d_in[2];
  const float* q_scale = (const float*)d_in[3];
  const float* k_scale = (const float*)d_in[4];
  const float* Wout    = (const float*)d_in[5];
  const float* bout    = (const float*)d_in[6];
  float* out = (float*)d_out;

  float* ws = (float*)d_ws;
  float* qkv = ws;                                       // [4096, 3072] fp32
  const size_t qkvN = (size_t)(CB * CS) * (3 * CDM);     // 12.58M floats
  const size_t perA = (size_t)CB * CH * CS * CHD;        // 4.19M ushorts
  ushort* Qh  = (ushort*)(ws + qkvN);
  ushort* Ql  = Qh + perA;
  ushort* Kh  = Ql + perA;
  ushort* Kl  = Kh + perA;
  ushort* Vth = Kl + perA;
  ushort* Vtl = Vth + perA;
  float* AO = ws;  // attention output [B,S,DM]; aliases qkv (dead after prep)

  // 1) qkv = x @ Wqkv^T + bqkv  (split-bf16 MFMA)
  dim3 g1((3 * CDM) / 128, (CB * CS) / 128);
  gemm_bt_bias_mfma<<<g1, 256, 0, stream>>>(x, Wqkv, bqkv, qkv,
                                            CB * CS, 3 * CDM, CDM);

  // 2) RMSNorm + RoPE; pre-split Q (scaled), K, Vt to bf16 h/l
  dim3 g2(CS / 64, CH, CB);
  qkv_prep<<<g2, 256, 0, stream>>>(qkv, q_scale, k_scale,
                                   Qh, Ql, Kh, Kl, Vth, Vtl);

  // 3) frame-block-causal attention on MFMA
  dim3 g3(CNF, CH, CB);
  attn_fwd_mfma<<<g3, 256, 0, stream>>>(Qh, Ql, Kh, Kl, Vth, Vtl, AO);

  // 4) out = AO @ Wout^T + bout  (split-bf16 MFMA)
  dim3 g4(CDM / 128, (CB * CS) / 128);
  gemm_bt_bias_mfma<<<g4, 256, 0, stream>>>(AO, Wout, bout, out,
                                            CB * CS, CDM, CDM);
}

// Round 11
// 287.230 us; speedup vs baseline: 35.5159x; 1.1016x over previous
//
#include <hip/hip_runtime.h>
#include <cstddef>
#include <cstdint>

// Problem constants (match reference)
constexpr int CB  = 2;     // batch
constexpr int CS  = 2048;  // seq len
constexpr int CDM = 1024;  // d_model
constexpr int CH  = 16;    // heads
constexpr int CHD = 64;    // head dim
constexpr int CTPF = 128;  // tokens per frame
constexpr int CNF = 16;    // frames

typedef __attribute__((ext_vector_type(8))) short short8;
typedef __attribute__((ext_vector_type(4))) float f32x4;

__device__ inline ushort f32_bf16_rne(float x) {
  uint32_t u = __float_as_uint(x);
  u += 0x7FFFu + ((u >> 16) & 1u);
  return (ushort)(u >> 16);
}
__device__ inline float bf16_f32(ushort h) {
  return __uint_as_float(((uint32_t)h) << 16);
}
// split 8 floats into hi/lo bf16 vectors
__device__ inline void split8(const float* v, short8& H, short8& L) {
#pragma unroll
  for (int j = 0; j < 8; ++j) {
    const ushort hh = f32_bf16_rne(v[j]);
    H[j] = (short)hh;
    L[j] = (short)f32_bf16_rne(v[j] - bf16_f32(hh));
  }
}

// ---------------------------------------------------------------------------
// split_pass: fp32 -> bf16 hi/lo, memory-bound grid-stride. Runs ONCE per
// matrix so the GEMM inner loop never pays split VALU (R9 diagnosis:
// in-loop split8 ~220 VALU ops/thread/K-step > MFMA cycles).
// ---------------------------------------------------------------------------
__global__ __launch_bounds__(256) void split_pass(
    const float* __restrict__ src, ushort* __restrict__ h,
    ushort* __restrict__ l, int n8) {
  int i = blockIdx.x * 256 + threadIdx.x;
  const int stride = gridDim.x * 256;
  for (; i < n8; i += stride) {
    float v[8];
    *(float4*)&v[0] = ((const float4*)src)[2 * i];
    *(float4*)&v[4] = ((const float4*)src)[2 * i + 1];
    short8 H, L;
    split8(v, H, L);
    *(short8*)&h[(size_t)i * 8] = H;
    *(short8*)&l[(size_t)i * 8] = L;
  }
}

// ---------------------------------------------------------------------------
// gemm_ps: C[M,N] = A[M,K] @ B[N,K]^T + bias[N], pre-split bf16 h/l inputs.
// Same 3-term split MFMA math as the validated R7 kernel (bit-identical),
// but staging is pure short8 copies into a combined h|l [128][64] tile with
// the 64-stride XOR swizzle (col ^ ((row&7)<<3)), write+read consistent.
// Bank check: reads 4(lk^(i&7)) uniform-8 over banks; writes 4(c^(r&7))
// uniform-8 -> both conflict-free. LDS 32 KB -> 5 blocks/CU.
// ---------------------------------------------------------------------------
__global__ __launch_bounds__(256) void gemm_ps(
    const ushort* __restrict__ Ah, const ushort* __restrict__ Al,
    const ushort* __restrict__ Bh, const ushort* __restrict__ Bl,
    const float* __restrict__ bias, float* __restrict__ C,
    int M, int N, int K) {
  __shared__ ushort As[128 * 64];
  __shared__ ushort Bs[128 * 64];
  const int tid = threadIdx.x;
  const int bm = blockIdx.y * 128;
  const int bn = blockIdx.x * 128;
  const int wid = tid >> 6;
  const int lane = tid & 63;
  const int wm = wid >> 1;
  const int wn = wid & 1;
  const int l15 = lane & 15;
  const int lk = lane >> 4;

  f32x4 acc[4][4];
#pragma unroll
  for (int i = 0; i < 4; ++i)
#pragma unroll
    for (int j = 0; j < 4; ++j) acc[i][j] = (f32x4){0.f, 0.f, 0.f, 0.f};

  for (int k0 = 0; k0 < K; k0 += 32) {
    __syncthreads();
#pragma unroll
    for (int c = 0; c < 2; ++c) {
      const int lin = tid + c * 256;
      const int row = lin >> 2;
      const int kq = (lin & 3) * 8;
      const int mk = (row & 7) << 3;
      const size_t ga = (size_t)(bm + row) * K + k0 + kq;
      *(short8*)&As[row * 64 + (kq ^ mk)] = *(const short8*)(Ah + ga);
      *(short8*)&As[row * 64 + ((kq + 32) ^ mk)] = *(const short8*)(Al + ga);
      const size_t gb = (size_t)(bn + row) * K + k0 + kq;
      *(short8*)&Bs[row * 64 + (kq ^ mk)] = *(const short8*)(Bh + gb);
      *(short8*)&Bs[row * 64 + ((kq + 32) ^ mk)] = *(const short8*)(Bl + gb);
    }
    __syncthreads();

    short8 ah[4], al[4], bh[4], bl[4];
#pragma unroll
    for (int fI = 0; fI < 4; ++fI) {
      const int ar = wm * 64 + fI * 16 + l15;
      const int am = (ar & 7) << 3;
      ah[fI] = *(const short8*)&As[ar * 64 + ((lk * 8) ^ am)];
      al[fI] = *(const short8*)&As[ar * 64 + ((lk * 8 + 32) ^ am)];
      const int br = wn * 64 + fI * 16 + l15;
      const int bmk = (br & 7) << 3;
      bh[fI] = *(const short8*)&Bs[br * 64 + ((lk * 8) ^ bmk)];
      bl[fI] = *(const short8*)&Bs[br * 64 + ((lk * 8 + 32) ^ bmk)];
    }
#pragma unroll
    for (int mf = 0; mf < 4; ++mf)
#pragma unroll
      for (int nf = 0; nf < 4; ++nf) {
        acc[mf][nf] = __builtin_amdgcn_mfma_f32_16x16x32_bf16(
            ah[mf], bh[nf], acc[mf][nf], 0, 0, 0);
        acc[mf][nf] = __builtin_amdgcn_mfma_f32_16x16x32_bf16(
            ah[mf], bl[nf], acc[mf][nf], 0, 0, 0);
        acc[mf][nf] = __builtin_amdgcn_mfma_f32_16x16x32_bf16(
            al[mf], bh[nf], acc[mf][nf], 0, 0, 0);
      }
  }

#pragma unroll
  for (int mf = 0; mf < 4; ++mf)
#pragma unroll
    for (int nf = 0; nf < 4; ++nf) {
      const int col = bn + wn * 64 + nf * 16 + l15;
      const int row0 = bm + wm * 64 + mf * 16 + lk * 4;
      const float bc = bias[col];
#pragma unroll
      for (int i = 0; i < 4; ++i)
        C[(size_t)(row0 + i) * N + col] = acc[mf][nf][i] + bc;
    }
}

// ---------------------------------------------------------------------------
// qkv_prep v3: RMSNorm + RoPE, then PRE-SPLIT everything to bf16 h/l:
//   Qh/Ql [B,H,S,64] (pre-scaled by HD^-0.5), Kh/Kl [B,H,S,64],
//   Vth/Vtl [B,H,64,S] (transposed for PV's B-operand).
// ---------------------------------------------------------------------------
__global__ __launch_bounds__(256) void qkv_prep(
    const float* __restrict__ qkv, const float* __restrict__ q_scale,
    const float* __restrict__ k_scale,
    ushort* __restrict__ Qh, ushort* __restrict__ Ql,
    ushort* __restrict__ Kh, ushort* __restrict__ Kl,
    ushort* __restrict__ Vth, ushort* __restrict__ Vtl) {
  __shared__ float Vtile[64][68];
  const int lane = threadIdx.x & 63;
  const int w = threadIdx.x >> 6;
  const int st = blockIdx.x;   // s-tile of 64
  const int h = blockIdx.y;
  const int b = blockIdx.z;

  const float qs = q_scale[lane];
  const float ks = k_scale[lane];
  const int j = lane & 31;
  const float inv = powf(10000.0f, -(float)j * (1.0f / 32.0f));
  const float sgn = (lane < 32) ? -1.f : 1.f;

  for (int it = 0; it < 16; ++it) {
    const int sl = w * 16 + it;
    const int s = st * 64 + sl;
    const size_t row =
        ((size_t)(b * CS + s)) * (3 * CDM) + (size_t)h * CHD + lane;
    float qv = qkv[row];
    float kv = qkv[row + CDM];
    const float vv = qkv[row + 2 * CDM];

    float sq = qv * qv, sk2 = kv * kv;
#pragma unroll
    for (int off = 32; off > 0; off >>= 1) {
      sq += __shfl_xor(sq, off);
      sk2 += __shfl_xor(sk2, off);
    }
    qv *= rsqrtf(sq * (1.f / CHD) + 1e-6f) * qs;
    kv *= rsqrtf(sk2 * (1.f / CHD) + 1e-6f) * ks;

    const float ang = (float)s * inv;
    const float cs = cosf(ang);
    const float sn = sinf(ang);
    const float qp = __shfl_xor(qv, 32);
    const float kp = __shfl_xor(kv, 32);
    const float qr = fmaf(qv, cs, sgn * qp * sn) * 0.125f;  // pre-scale Q
    const float kr = fmaf(kv, cs, sgn * kp * sn);

    const size_t ob = (((size_t)(b * CH + h)) * CS + s) * CHD + lane;
    const ushort qhh = f32_bf16_rne(qr);
    Qh[ob] = qhh;
    Ql[ob] = f32_bf16_rne(qr - bf16_f32(qhh));
    const ushort khh = f32_bf16_rne(kr);
    Kh[ob] = khh;
    Kl[ob] = f32_bf16_rne(kr - bf16_f32(khh));
    Vtile[lane][sl] = vv;
  }
  __syncthreads();
  // write Vt[b,h,d, st*64 .. +63] split h/l, coalesced
  const int d = threadIdx.x >> 2;
  const int sq4 = (threadIdx.x & 3) * 16;
  const size_t vb = (((size_t)(b * CH + h)) * CHD + d) * CS + st * 64 + sq4;
#pragma unroll
  for (int j0 = 0; j0 < 16; j0 += 8) {
    float v8[8];
#pragma unroll
    for (int jj = 0; jj < 8; ++jj) v8[jj] = Vtile[d][sq4 + j0 + jj];
    short8 H, L;
    split8(v8, H, L);
    *(short8*)&Vth[vb + j0] = H;
    *(short8*)&Vtl[vb + j0] = L;
  }
}

// ---------------------------------------------------------------------------
// attn_fwd_mfma v3: identical math to R9 (swapped QK^T, XOR-swizzled LDS,
// 3-term split). Single change: epilogue writes O pre-split to bf16 h/l
// (same rne split GEMM2's staging performed before -> bit-identical), so
// GEMM2 stages pure copies.
// ---------------------------------------------------------------------------
__global__ __launch_bounds__(256, 2) void attn_fwd_mfma(
    const ushort* __restrict__ Qh, const ushort* __restrict__ Ql,
    const ushort* __restrict__ Kh, const ushort* __restrict__ Kl,
    const ushort* __restrict__ Vth, const ushort* __restrict__ Vtl,
    ushort* __restrict__ Oh, ushort* __restrict__ Ol) {
  __shared__ ushort Ks_h[64 * 64], Ks_l[64 * 64];   // K chunk [key][d]
  __shared__ ushort Vs_h[64 * 64], Vs_l[64 * 64];   // V^T chunk [d][key]
  __shared__ ushort Ps_h[128 * 64], Ps_l[128 * 64]; // P [q][key], wave-priv
  const int tid = threadIdx.x;
  const int f = (CNF - 1) - blockIdx.x;  // heavy frames first
  const int h = blockIdx.y;
  const int b = blockIdx.z;
  const int lane = tid & 63;
  const int wid = tid >> 6;
  const int l15 = lane & 15;
  const int lk = lane >> 4;
  const int qb = wid * 32;  // wave's queries within the frame
  const size_t hb = ((size_t)(b * CH + h)) * CS * CHD;   // Q/K [b,h,s,d]
  const size_t vtb = ((size_t)(b * CH + h)) * CHD * CS;  // Vt [b,h,d,s]

  // Q B-frags straight from pre-split global (already scaled by HD^-0.5).
  short8 qh[2][2], ql[2][2];
#pragma unroll
  for (int nf = 0; nf < 2; ++nf)
#pragma unroll
    for (int ks = 0; ks < 2; ++ks) {
      const size_t qoff = hb +
          (size_t)(f * CTPF + qb + nf * 16 + l15) * CHD + ks * 32 + lk * 8;
      qh[nf][ks] = *(const short8*)(Qh + qoff);
      ql[nf][ks] = *(const short8*)(Ql + qoff);
    }

  f32x4 accO[2][4];
#pragma unroll
  for (int mo = 0; mo < 2; ++mo)
#pragma unroll
    for (int no = 0; no < 4; ++no) accO[mo][no] = (f32x4){0.f, 0.f, 0.f, 0.f};
  float m[2] = {-1e30f, -1e30f};
  float lsum[2] = {0.f, 0.f};

  const int kf0 = (f == CNF - 1) ? 1 : 0;  // last-frame quirk
  for (int kf = kf0; kf <= f; ++kf) {
#pragma unroll 1
    for (int half = 0; half < 2; ++half) {
      const int cb = kf * CTPF + half * 64;  // chunk base key
      __syncthreads();  // prev chunk's K/V readers done
      {
        const int r = tid >> 2;            // 0..63
        const int cq = (tid & 3) * 16;     // 0,16,32,48
        const int mk = (r & 7) << 3;       // XOR swizzle (ushort units)
        // K: rows = key, cols = d
        const size_t ko = hb + (size_t)(cb + r) * CHD + cq;
        *(short8*)&Ks_h[r * 64 + (cq ^ mk)] = *(const short8*)(Kh + ko);
        *(short8*)&Ks_h[r * 64 + ((cq + 8) ^ mk)] = *(const short8*)(Kh + ko + 8);
        *(short8*)&Ks_l[r * 64 + (cq ^ mk)] = *(const short8*)(Kl + ko);
        *(short8*)&Ks_l[r * 64 + ((cq + 8) ^ mk)] = *(const short8*)(Kl + ko + 8);
        // V^T: rows = d, cols = key
        const size_t vo = vtb + (size_t)r * CS + cb + cq;
        *(short8*)&Vs_h[r * 64 + (cq ^ mk)] = *(const short8*)(Vth + vo);
        *(short8*)&Vs_h[r * 64 + ((cq + 8) ^ mk)] = *(const short8*)(Vth + vo + 8);
        *(short8*)&Vs_l[r * 64 + (cq ^ mk)] = *(const short8*)(Vtl + vo);
        *(short8*)&Vs_l[r * 64 + ((cq + 8) ^ mk)] = *(const short8*)(Vtl + vo + 8);
      }
      __syncthreads();

      // QK^T swapped: S^T[key][q]; acc frags [mf=key/16][nf=q/16]
      f32x4 sacc[4][2];
#pragma unroll
      for (int mf = 0; mf < 4; ++mf)
#pragma unroll
        for (int nf = 0; nf < 2; ++nf) sacc[mf][nf] = (f32x4){0.f, 0.f, 0.f, 0.f};
#pragma unroll
      for (int ks = 0; ks < 2; ++ks) {
        short8 kh[4], kl[4];
#pragma unroll
        for (int mf = 0; mf < 4; ++mf) {
          const int krow = mf * 16 + l15;
          const int base = krow * 64 + ((ks * 32 + lk * 8) ^ ((krow & 7) << 3));
          kh[mf] = *(const short8*)&Ks_h[base];
          kl[mf] = *(const short8*)&Ks_l[base];
        }
#pragma unroll
        for (int mf = 0; mf < 4; ++mf)
#pragma unroll
          for (int nf = 0; nf < 2; ++nf) {
            sacc[mf][nf] = __builtin_amdgcn_mfma_f32_16x16x32_bf16(
                kh[mf], qh[nf][ks], sacc[mf][nf], 0, 0, 0);
            sacc[mf][nf] = __builtin_amdgcn_mfma_f32_16x16x32_bf16(
                kh[mf], ql[nf][ks], sacc[mf][nf], 0, 0, 0);
            sacc[mf][nf] = __builtin_amdgcn_mfma_f32_16x16x32_bf16(
                kl[mf], qh[nf][ks], sacc[mf][nf], 0, 0, 0);
          }
      }

      // online softmax per query column (nf): in-lane 16 keys + lk reduce
      float c[2];
#pragma unroll
      for (int nf = 0; nf < 2; ++nf) {
        float cm = sacc[0][nf][0];
#pragma unroll
        for (int mf = 0; mf < 4; ++mf)
#pragma unroll
          for (int i = 0; i < 4; ++i) cm = fmaxf(cm, sacc[mf][nf][i]);
        cm = fmaxf(cm, __shfl_xor(cm, 16));
        cm = fmaxf(cm, __shfl_xor(cm, 32));
        const float mn = fmaxf(m[nf], cm);
        c[nf] = __expf(m[nf] - mn);
        m[nf] = mn;
        float ps = 0.f;
        const int qrow = qb + nf * 16 + l15;
        const int qmk = (qrow & 7) << 3;
#pragma unroll
        for (int mf = 0; mf < 4; ++mf) {
          float p0 = __expf(sacc[mf][nf][0] - mn);
          float p1 = __expf(sacc[mf][nf][1] - mn);
          float p2 = __expf(sacc[mf][nf][2] - mn);
          float p3 = __expf(sacc[mf][nf][3] - mn);
          ps += (p0 + p1) + (p2 + p3);
          const ushort h0 = f32_bf16_rne(p0), h1 = f32_bf16_rne(p1);
          const ushort h2 = f32_bf16_rne(p2), h3 = f32_bf16_rne(p3);
          uint2 hw, lw;
          hw.x = (uint32_t)h0 | ((uint32_t)h1 << 16);
          hw.y = (uint32_t)h2 | ((uint32_t)h3 << 16);
          lw.x = (uint32_t)f32_bf16_rne(p0 - bf16_f32(h0)) |
                 ((uint32_t)f32_bf16_rne(p1 - bf16_f32(h1)) << 16);
          lw.y = (uint32_t)f32_bf16_rne(p2 - bf16_f32(h2)) |
                 ((uint32_t)f32_bf16_rne(p3 - bf16_f32(h3)) << 16);
          const int off = qrow * 64 + ((mf * 16 + lk * 4) ^ qmk);
          *(uint2*)&Ps_h[off] = hw;
          *(uint2*)&Ps_l[off] = lw;
        }
        ps += __shfl_xor(ps, 16);
        ps += __shfl_xor(ps, 32);
        lsum[nf] = lsum[nf] * c[nf] + ps;
      }
      // rescale O accumulator
#pragma unroll
      for (int mo = 0; mo < 2; ++mo)
#pragma unroll
        for (int i = 0; i < 4; ++i) {
          const float cq = __shfl(c[mo], lk * 4 + i);
#pragma unroll
          for (int no = 0; no < 4; ++no) accO[mo][no][i] *= cq;
        }

      // PV: O[q][d] += P[q][key] * Vt[d][key]
#pragma unroll
      for (int ks = 0; ks < 2; ++ks) {
        short8 pa_h[2], pa_l[2], vb_h[4], vb_l[4];
#pragma unroll
        for (int mo = 0; mo < 2; ++mo) {
          const int qrow = qb + mo * 16 + l15;
          const int base = qrow * 64 + ((ks * 32 + lk * 8) ^ ((qrow & 7) << 3));
          pa_h[mo] = *(const short8*)&Ps_h[base];
          pa_l[mo] = *(const short8*)&Ps_l[base];
        }
#pragma unroll
        for (int no = 0; no < 4; ++no) {
          const int vrow = no * 16 + l15;
          const int base = vrow * 64 + ((ks * 32 + lk * 8) ^ ((vrow & 7) << 3));
          vb_h[no] = *(const short8*)&Vs_h[base];
          vb_l[no] = *(const short8*)&Vs_l[base];
        }
#pragma unroll
        for (int mo = 0; mo < 2; ++mo)
#pragma unroll
          for (int no = 0; no < 4; ++no) {
            accO[mo][no] = __builtin_amdgcn_mfma_f32_16x16x32_bf16(
                pa_h[mo], vb_h[no], accO[mo][no], 0, 0, 0);
            accO[mo][no] = __builtin_amdgcn_mfma_f32_16x16x32_bf16(
                pa_h[mo], vb_l[no], accO[mo][no], 0, 0, 0);
            accO[mo][no] = __builtin_amdgcn_mfma_f32_16x16x32_bf16(
                pa_l[mo], vb_h[no], accO[mo][no], 0, 0, 0);
          }
      }
    }
  }

  // normalize and write O pre-split h/l in [B,S,DM] layout for GEMM2
  const float il0 = 1.f / lsum[0];
  const float il1 = 1.f / lsum[1];
#pragma unroll
  for (int mo = 0; mo < 2; ++mo) {
    const float myil = (mo == 0) ? il0 : il1;
#pragma unroll
    for (int i = 0; i < 4; ++i) {
      const float wv = __shfl(myil, lk * 4 + i);
      const int srow = f * CTPF + qb + mo * 16 + lk * 4 + i;
      const size_t obase = (size_t)(b * CS + srow) * CDM + h * CHD;
#pragma unroll
      for (int no = 0; no < 4; ++no) {
        const float val = accO[mo][no][i] * wv;
        const ushort hh = f32_bf16_rne(val);
        Oh[obase + no * 16 + l15] = hh;
        Ol[obase + no * 16 + l15] = f32_bf16_rne(val - bf16_f32(hh));
      }
    }
  }
}

// ---------------------------------------------------------------------------
extern "C" void kernel_launch(void* const* d_in, const int* in_sizes, int n_in,
                              void* d_out, int out_size, void* d_ws, size_t ws_size,
                              hipStream_t stream) {
  const float* x       = (const float*)d_in[0];
  const float* Wqkv    = (const float*)d_in[1];
  const float* bqkv    = (const float*)d_in[2];
  const float* q_scale = (const float*)d_in[3];
  const float* k_scale = (const float*)d_in[4];
  const float* Wout    = (const float*)d_in[5];
  const float* bout    = (const float*)d_in[6];
  float* out = (float*)d_out;

  // Workspace layout (ushort units). Temporal aliasing:
  //  region0 (50.3 MB): qkv fp32 [live GEMM1..prep]  ->  Oh/Ol [live attn..GEMM2]
  //  region1 (50.3 MB): xh/xl/Wqh/Wql [live split..GEMM1] -> Qh..Vtl [prep..attn]
  //  region2 ( 4.2 MB): Wouth/Woutl [live split..GEMM2]
  ushort* W = (ushort*)d_ws;
  const size_t qkvN = (size_t)(CB * CS) * (3 * CDM);   // 12.58M floats
  const size_t perA = (size_t)CB * CH * CS * CHD;      // 4.19M elems
  const size_t WqN  = (size_t)(3 * CDM) * CDM;         // 3.15M
  const size_t WoN  = (size_t)CDM * CDM;               // 1.05M

  float*  qkvF = (float*)W;
  ushort* Oh   = W;                    // aliases qkvF (dead after prep)
  ushort* Ol   = W + perA;
  ushort* R1   = W + 2 * qkvN;
  ushort* Qh = R1;            ushort* Ql = R1 + perA;
  ushort* Kh = R1 + 2 * perA; ushort* Kl = R1 + 3 * perA;
  ushort* Vth = R1 + 4 * perA; ushort* Vtl = R1 + 5 * perA;
  ushort* xh  = R1;            ushort* xl  = R1 + perA;   // alias Qh/Ql
  ushort* Wqh = R1 + 2 * perA; ushort* Wql = Wqh + WqN;   // alias Kh..
  ushort* Wouth = R1 + 6 * perA; ushort* Woutl = Wouth + WoN;

  // 0) one-time fp32 -> bf16 h/l splits (memory-bound)
  split_pass<<<2048, 256, 0, stream>>>(x, xh, xl, (int)(perA / 8));
  split_pass<<<1536, 256, 0, stream>>>(Wqkv, Wqh, Wql, (int)(WqN / 8));
  split_pass<<<512, 256, 0, stream>>>(Wout, Wouth, Woutl, (int)(WoN / 8));

  // 1) qkv = x @ Wqkv^T + bqkv
  dim3 g1((3 * CDM) / 128, (CB * CS) / 128);
  gemm_ps<<<g1, 256, 0, stream>>>(xh, xl, Wqh, Wql, bqkv, qkvF,
                                  CB * CS, 3 * CDM, CDM);

  // 2) RMSNorm + RoPE; pre-split Q (scaled), K, Vt to bf16 h/l
  dim3 g2(CS / 64, CH, CB);
  qkv_prep<<<g2, 256, 0, stream>>>(qkvF, q_scale, k_scale,
                                   Qh, Ql, Kh, Kl, Vth, Vtl);

  // 3) frame-block-causal attention on MFMA -> pre-split O
  dim3 g3(CNF, CH, CB);
  attn_fwd_mfma<<<g3, 256, 0, stream>>>(Qh, Ql, Kh, Kl, Vth, Vtl, Oh, Ol);

  // 4) out = O @ Wout^T + bout
  dim3 g4(CDM / 128, (CB * CS) / 128);
  gemm_ps<<<g4, 256, 0, stream>>>(Oh, Ol, Wouth, Woutl, bout, out,
                                  CB * CS, CDM, CDM);
}

// Round 12
// 254.696 us; speedup vs baseline: 40.0527x; 1.1277x over previous
//
#include <hip/hip_runtime.h>
#include <cstddef>
#include <cstdint>

// Problem constants (match reference)
constexpr int CB  = 2;     // batch
constexpr int CS  = 2048;  // seq len
constexpr int CDM = 1024;  // d_model
constexpr int CH  = 16;    // heads
constexpr int CHD = 64;    // head dim
constexpr int CTPF = 128;  // tokens per frame
constexpr int CNF = 16;    // frames

typedef __attribute__((ext_vector_type(8))) short short8;
typedef __attribute__((ext_vector_type(4))) float f32x4;

__device__ inline ushort f32_bf16_rne(float x) {
  uint32_t u = __float_as_uint(x);
  u += 0x7FFFu + ((u >> 16) & 1u);
  return (ushort)(u >> 16);
}
__device__ inline float bf16_f32(ushort h) {
  return __uint_as_float(((uint32_t)h) << 16);
}
// split 8 floats into hi/lo bf16 vectors
__device__ inline void split8(const float* v, short8& H, short8& L) {
#pragma unroll
  for (int j = 0; j < 8; ++j) {
    const ushort hh = f32_bf16_rne(v[j]);
    H[j] = (short)hh;
    L[j] = (short)f32_bf16_rne(v[j] - bf16_f32(hh));
  }
}

// ---------------------------------------------------------------------------
// split_pass: fp32 -> bf16 hi/lo, memory-bound grid-stride. Runs ONCE per
// matrix so the GEMM inner loop never pays split VALU.
// ---------------------------------------------------------------------------
__global__ __launch_bounds__(256) void split_pass(
    const float* __restrict__ src, ushort* __restrict__ h,
    ushort* __restrict__ l, int n8) {
  int i = blockIdx.x * 256 + threadIdx.x;
  const int stride = gridDim.x * 256;
  for (; i < n8; i += stride) {
    float v[8];
    *(float4*)&v[0] = ((const float4*)src)[2 * i];
    *(float4*)&v[4] = ((const float4*)src)[2 * i + 1];
    short8 H, L;
    split8(v, H, L);
    *(short8*)&h[(size_t)i * 8] = H;
    *(short8*)&l[(size_t)i * 8] = L;
  }
}

// ---------------------------------------------------------------------------
// gemm_ps: C[M,N] = A[M,K] @ B[N,K]^T + bias[N], pre-split bf16 h/l inputs.
// (validated R11: 3-term split MFMA, XOR-swizzled 32 KB LDS)
// ---------------------------------------------------------------------------
__global__ __launch_bounds__(256) void gemm_ps(
    const ushort* __restrict__ Ah, const ushort* __restrict__ Al,
    const ushort* __restrict__ Bh, const ushort* __restrict__ Bl,
    const float* __restrict__ bias, float* __restrict__ C,
    int M, int N, int K) {
  __shared__ ushort As[128 * 64];
  __shared__ ushort Bs[128 * 64];
  const int tid = threadIdx.x;
  const int bm = blockIdx.y * 128;
  const int bn = blockIdx.x * 128;
  const int wid = tid >> 6;
  const int lane = tid & 63;
  const int wm = wid >> 1;
  const int wn = wid & 1;
  const int l15 = lane & 15;
  const int lk = lane >> 4;

  f32x4 acc[4][4];
#pragma unroll
  for (int i = 0; i < 4; ++i)
#pragma unroll
    for (int j = 0; j < 4; ++j) acc[i][j] = (f32x4){0.f, 0.f, 0.f, 0.f};

  for (int k0 = 0; k0 < K; k0 += 32) {
    __syncthreads();
#pragma unroll
    for (int c = 0; c < 2; ++c) {
      const int lin = tid + c * 256;
      const int row = lin >> 2;
      const int kq = (lin & 3) * 8;
      const int mk = (row & 7) << 3;
      const size_t ga = (size_t)(bm + row) * K + k0 + kq;
      *(short8*)&As[row * 64 + (kq ^ mk)] = *(const short8*)(Ah + ga);
      *(short8*)&As[row * 64 + ((kq + 32) ^ mk)] = *(const short8*)(Al + ga);
      const size_t gb = (size_t)(bn + row) * K + k0 + kq;
      *(short8*)&Bs[row * 64 + (kq ^ mk)] = *(const short8*)(Bh + gb);
      *(short8*)&Bs[row * 64 + ((kq + 32) ^ mk)] = *(const short8*)(Bl + gb);
    }
    __syncthreads();

    short8 ah[4], al[4], bh[4], bl[4];
#pragma unroll
    for (int fI = 0; fI < 4; ++fI) {
      const int ar = wm * 64 + fI * 16 + l15;
      const int am = (ar & 7) << 3;
      ah[fI] = *(const short8*)&As[ar * 64 + ((lk * 8) ^ am)];
      al[fI] = *(const short8*)&As[ar * 64 + ((lk * 8 + 32) ^ am)];
      const int br = wn * 64 + fI * 16 + l15;
      const int bmk = (br & 7) << 3;
      bh[fI] = *(const short8*)&Bs[br * 64 + ((lk * 8) ^ bmk)];
      bl[fI] = *(const short8*)&Bs[br * 64 + ((lk * 8 + 32) ^ bmk)];
    }
#pragma unroll
    for (int mf = 0; mf < 4; ++mf)
#pragma unroll
      for (int nf = 0; nf < 4; ++nf) {
        acc[mf][nf] = __builtin_amdgcn_mfma_f32_16x16x32_bf16(
            ah[mf], bh[nf], acc[mf][nf], 0, 0, 0);
        acc[mf][nf] = __builtin_amdgcn_mfma_f32_16x16x32_bf16(
            ah[mf], bl[nf], acc[mf][nf], 0, 0, 0);
        acc[mf][nf] = __builtin_amdgcn_mfma_f32_16x16x32_bf16(
            al[mf], bh[nf], acc[mf][nf], 0, 0, 0);
      }
  }

#pragma unroll
  for (int mf = 0; mf < 4; ++mf)
#pragma unroll
    for (int nf = 0; nf < 4; ++nf) {
      const int col = bn + wn * 64 + nf * 16 + l15;
      const int row0 = bm + wm * 64 + mf * 16 + lk * 4;
      const float bc = bias[col];
#pragma unroll
      for (int i = 0; i < 4; ++i)
        C[(size_t)(row0 + i) * N + col] = acc[mf][nf][i] + bc;
    }
}

// ---------------------------------------------------------------------------
// qkv_prep v3: RMSNorm + RoPE, then PRE-SPLIT everything to bf16 h/l:
//   Qh/Ql [B,H,S,64] (pre-scaled by HD^-0.5), Kh/Kl [B,H,S,64],
//   Vth/Vtl [B,H,64,S] (transposed for PV's B-operand).
// ---------------------------------------------------------------------------
__global__ __launch_bounds__(256) void qkv_prep(
    const float* __restrict__ qkv, const float* __restrict__ q_scale,
    const float* __restrict__ k_scale,
    ushort* __restrict__ Qh, ushort* __restrict__ Ql,
    ushort* __restrict__ Kh, ushort* __restrict__ Kl,
    ushort* __restrict__ Vth, ushort* __restrict__ Vtl) {
  __shared__ float Vtile[64][68];
  const int lane = threadIdx.x & 63;
  const int w = threadIdx.x >> 6;
  const int st = blockIdx.x;   // s-tile of 64
  const int h = blockIdx.y;
  const int b = blockIdx.z;

  const float qs = q_scale[lane];
  const float ks = k_scale[lane];
  const int j = lane & 31;
  const float inv = powf(10000.0f, -(float)j * (1.0f / 32.0f));
  const float sgn = (lane < 32) ? -1.f : 1.f;

  for (int it = 0; it < 16; ++it) {
    const int sl = w * 16 + it;
    const int s = st * 64 + sl;
    const size_t row =
        ((size_t)(b * CS + s)) * (3 * CDM) + (size_t)h * CHD + lane;
    float qv = qkv[row];
    float kv = qkv[row + CDM];
    const float vv = qkv[row + 2 * CDM];

    float sq = qv * qv, sk2 = kv * kv;
#pragma unroll
    for (int off = 32; off > 0; off >>= 1) {
      sq += __shfl_xor(sq, off);
      sk2 += __shfl_xor(sk2, off);
    }
    qv *= rsqrtf(sq * (1.f / CHD) + 1e-6f) * qs;
    kv *= rsqrtf(sk2 * (1.f / CHD) + 1e-6f) * ks;

    const float ang = (float)s * inv;
    const float cs = cosf(ang);
    const float sn = sinf(ang);
    const float qp = __shfl_xor(qv, 32);
    const float kp = __shfl_xor(kv, 32);
    const float qr = fmaf(qv, cs, sgn * qp * sn) * 0.125f;  // pre-scale Q
    const float kr = fmaf(kv, cs, sgn * kp * sn);

    const size_t ob = (((size_t)(b * CH + h)) * CS + s) * CHD + lane;
    const ushort qhh = f32_bf16_rne(qr);
    Qh[ob] = qhh;
    Ql[ob] = f32_bf16_rne(qr - bf16_f32(qhh));
    const ushort khh = f32_bf16_rne(kr);
    Kh[ob] = khh;
    Kl[ob] = f32_bf16_rne(kr - bf16_f32(khh));
    Vtile[lane][sl] = vv;
  }
  __syncthreads();
  // write Vt[b,h,d, st*64 .. +63] split h/l, coalesced
  const int d = threadIdx.x >> 2;
  const int sq4 = (threadIdx.x & 3) * 16;
  const size_t vb = (((size_t)(b * CH + h)) * CHD + d) * CS + st * 64 + sq4;
#pragma unroll
  for (int j0 = 0; j0 < 16; j0 += 8) {
    float v8[8];
#pragma unroll
    for (int jj = 0; jj < 8; ++jj) v8[jj] = Vtile[d][sq4 + j0 + jj];
    short8 H, L;
    split8(v8, H, L);
    *(short8*)&Vth[vb + j0] = H;
    *(short8*)&Vtl[vb + j0] = L;
  }
}

// ---------------------------------------------------------------------------
// attn_fwd_mfma v4: identical math to R11. Single change: LOAD BALANCE.
// R11 diagnosis: grid (frame, head, batch) linearizes so block c and c+256
// (which land on the same CU under any mod-256 round-robin, incl. XCD
// interleave: same c%8 -> same XCD, same (c/8)%32 -> same CU) carry the
// SAME frame -> the f=15 CU does 60 chunk-units vs mean 34 (makespan-bound,
// 138 us vs ~80 ideal). New grid (batch, head, fsel) with
// f = fsel<8 ? 15-fsel : fsel-8 pairs complementary frames {15-a, a} on one
// CU = 17+17 units everywhere.
// ---------------------------------------------------------------------------
__global__ __launch_bounds__(256, 2) void attn_fwd_mfma(
    const ushort* __restrict__ Qh, const ushort* __restrict__ Ql,
    const ushort* __restrict__ Kh, const ushort* __restrict__ Kl,
    const ushort* __restrict__ Vth, const ushort* __restrict__ Vtl,
    ushort* __restrict__ Oh, ushort* __restrict__ Ol) {
  __shared__ ushort Ks_h[64 * 64], Ks_l[64 * 64];   // K chunk [key][d]
  __shared__ ushort Vs_h[64 * 64], Vs_l[64 * 64];   // V^T chunk [d][key]
  __shared__ ushort Ps_h[128 * 64], Ps_l[128 * 64]; // P [q][key], wave-priv
  const int tid = threadIdx.x;
  const int b = blockIdx.x;
  const int h = blockIdx.y;
  const int fsel = blockIdx.z;
  const int f = (fsel < 8) ? (15 - fsel) : (fsel - 8);  // balanced pairing
  const int lane = tid & 63;
  const int wid = tid >> 6;
  const int l15 = lane & 15;
  const int lk = lane >> 4;
  const int qb = wid * 32;  // wave's queries within the frame
  const size_t hb = ((size_t)(b * CH + h)) * CS * CHD;   // Q/K [b,h,s,d]
  const size_t vtb = ((size_t)(b * CH + h)) * CHD * CS;  // Vt [b,h,d,s]

  // Q B-frags straight from pre-split global (already scaled by HD^-0.5).
  short8 qh[2][2], ql[2][2];
#pragma unroll
  for (int nf = 0; nf < 2; ++nf)
#pragma unroll
    for (int ks = 0; ks < 2; ++ks) {
      const size_t qoff = hb +
          (size_t)(f * CTPF + qb + nf * 16 + l15) * CHD + ks * 32 + lk * 8;
      qh[nf][ks] = *(const short8*)(Qh + qoff);
      ql[nf][ks] = *(const short8*)(Ql + qoff);
    }

  f32x4 accO[2][4];
#pragma unroll
  for (int mo = 0; mo < 2; ++mo)
#pragma unroll
    for (int no = 0; no < 4; ++no) accO[mo][no] = (f32x4){0.f, 0.f, 0.f, 0.f};
  float m[2] = {-1e30f, -1e30f};
  float lsum[2] = {0.f, 0.f};

  const int kf0 = (f == CNF - 1) ? 1 : 0;  // last-frame quirk
  for (int kf = kf0; kf <= f; ++kf) {
#pragma unroll 1
    for (int half = 0; half < 2; ++half) {
      const int cb = kf * CTPF + half * 64;  // chunk base key
      __syncthreads();  // prev chunk's K/V readers done
      {
        const int r = tid >> 2;            // 0..63
        const int cq = (tid & 3) * 16;     // 0,16,32,48
        const int mk = (r & 7) << 3;       // XOR swizzle (ushort units)
        // K: rows = key, cols = d
        const size_t ko = hb + (size_t)(cb + r) * CHD + cq;
        *(short8*)&Ks_h[r * 64 + (cq ^ mk)] = *(const short8*)(Kh + ko);
        *(short8*)&Ks_h[r * 64 + ((cq + 8) ^ mk)] = *(const short8*)(Kh + ko + 8);
        *(short8*)&Ks_l[r * 64 + (cq ^ mk)] = *(const short8*)(Kl + ko);
        *(short8*)&Ks_l[r * 64 + ((cq + 8) ^ mk)] = *(const short8*)(Kl + ko + 8);
        // V^T: rows = d, cols = key
        const size_t vo = vtb + (size_t)r * CS + cb + cq;
        *(short8*)&Vs_h[r * 64 + (cq ^ mk)] = *(const short8*)(Vth + vo);
        *(short8*)&Vs_h[r * 64 + ((cq + 8) ^ mk)] = *(const short8*)(Vth + vo + 8);
        *(short8*)&Vs_l[r * 64 + (cq ^ mk)] = *(const short8*)(Vtl + vo);
        *(short8*)&Vs_l[r * 64 + ((cq + 8) ^ mk)] = *(const short8*)(Vtl + vo + 8);
      }
      __syncthreads();

      // QK^T swapped: S^T[key][q]; acc frags [mf=key/16][nf=q/16]
      f32x4 sacc[4][2];
#pragma unroll
      for (int mf = 0; mf < 4; ++mf)
#pragma unroll
        for (int nf = 0; nf < 2; ++nf) sacc[mf][nf] = (f32x4){0.f, 0.f, 0.f, 0.f};
#pragma unroll
      for (int ks = 0; ks < 2; ++ks) {
        short8 kh[4], kl[4];
#pragma unroll
        for (int mf = 0; mf < 4; ++mf) {
          const int krow = mf * 16 + l15;
          const int base = krow * 64 + ((ks * 32 + lk * 8) ^ ((krow & 7) << 3));
          kh[mf] = *(const short8*)&Ks_h[base];
          kl[mf] = *(const short8*)&Ks_l[base];
        }
#pragma unroll
        for (int mf = 0; mf < 4; ++mf)
#pragma unroll
          for (int nf = 0; nf < 2; ++nf) {
            sacc[mf][nf] = __builtin_amdgcn_mfma_f32_16x16x32_bf16(
                kh[mf], qh[nf][ks], sacc[mf][nf], 0, 0, 0);
            sacc[mf][nf] = __builtin_amdgcn_mfma_f32_16x16x32_bf16(
                kh[mf], ql[nf][ks], sacc[mf][nf], 0, 0, 0);
            sacc[mf][nf] = __builtin_amdgcn_mfma_f32_16x16x32_bf16(
                kl[mf], qh[nf][ks], sacc[mf][nf], 0, 0, 0);
          }
      }

      // online softmax per query column (nf): in-lane 16 keys + lk reduce
      float c[2];
#pragma unroll
      for (int nf = 0; nf < 2; ++nf) {
        float cm = sacc[0][nf][0];
#pragma unroll
        for (int mf = 0; mf < 4; ++mf)
#pragma unroll
          for (int i = 0; i < 4; ++i) cm = fmaxf(cm, sacc[mf][nf][i]);
        cm = fmaxf(cm, __shfl_xor(cm, 16));
        cm = fmaxf(cm, __shfl_xor(cm, 32));
        const float mn = fmaxf(m[nf], cm);
        c[nf] = __expf(m[nf] - mn);
        m[nf] = mn;
        float ps = 0.f;
        const int qrow = qb + nf * 16 + l15;
        const int qmk = (qrow & 7) << 3;
#pragma unroll
        for (int mf = 0; mf < 4; ++mf) {
          float p0 = __expf(sacc[mf][nf][0] - mn);
          float p1 = __expf(sacc[mf][nf][1] - mn);
          float p2 = __expf(sacc[mf][nf][2] - mn);
          float p3 = __expf(sacc[mf][nf][3] - mn);
          ps += (p0 + p1) + (p2 + p3);
          const ushort h0 = f32_bf16_rne(p0), h1 = f32_bf16_rne(p1);
          const ushort h2 = f32_bf16_rne(p2), h3 = f32_bf16_rne(p3);
          uint2 hw, lw;
          hw.x = (uint32_t)h0 | ((uint32_t)h1 << 16);
          hw.y = (uint32_t)h2 | ((uint32_t)h3 << 16);
          lw.x = (uint32_t)f32_bf16_rne(p0 - bf16_f32(h0)) |
                 ((uint32_t)f32_bf16_rne(p1 - bf16_f32(h1)) << 16);
          lw.y = (uint32_t)f32_bf16_rne(p2 - bf16_f32(h2)) |
                 ((uint32_t)f32_bf16_rne(p3 - bf16_f32(h3)) << 16);
          const int off = qrow * 64 + ((mf * 16 + lk * 4) ^ qmk);
          *(uint2*)&Ps_h[off] = hw;
          *(uint2*)&Ps_l[off] = lw;
        }
        ps += __shfl_xor(ps, 16);
        ps += __shfl_xor(ps, 32);
        lsum[nf] = lsum[nf] * c[nf] + ps;
      }
      // rescale O accumulator
#pragma unroll
      for (int mo = 0; mo < 2; ++mo)
#pragma unroll
        for (int i = 0; i < 4; ++i) {
          const float cq = __shfl(c[mo], lk * 4 + i);
#pragma unroll
          for (int no = 0; no < 4; ++no) accO[mo][no][i] *= cq;
        }

      // PV: O[q][d] += P[q][key] * Vt[d][key]
#pragma unroll
      for (int ks = 0; ks < 2; ++ks) {
        short8 pa_h[2], pa_l[2], vb_h[4], vb_l[4];
#pragma unroll
        for (int mo = 0; mo < 2; ++mo) {
          const int qrow = qb + mo * 16 + l15;
          const int base = qrow * 64 + ((ks * 32 + lk * 8) ^ ((qrow & 7) << 3));
          pa_h[mo] = *(const short8*)&Ps_h[base];
          pa_l[mo] = *(const short8*)&Ps_l[base];
        }
#pragma unroll
        for (int no = 0; no < 4; ++no) {
          const int vrow = no * 16 + l15;
          const int base = vrow * 64 + ((ks * 32 + lk * 8) ^ ((vrow & 7) << 3));
          vb_h[no] = *(const short8*)&Vs_h[base];
          vb_l[no] = *(const short8*)&Vs_l[base];
        }
#pragma unroll
        for (int mo = 0; mo < 2; ++mo)
#pragma unroll
          for (int no = 0; no < 4; ++no) {
            accO[mo][no] = __builtin_amdgcn_mfma_f32_16x16x32_bf16(
                pa_h[mo], vb_h[no], accO[mo][no], 0, 0, 0);
            accO[mo][no] = __builtin_amdgcn_mfma_f32_16x16x32_bf16(
                pa_h[mo], vb_l[no], accO[mo][no], 0, 0, 0);
            accO[mo][no] = __builtin_amdgcn_mfma_f32_16x16x32_bf16(
                pa_l[mo], vb_h[no], accO[mo][no], 0, 0, 0);
          }
      }
    }
  }

  // normalize and write O pre-split h/l in [B,S,DM] layout for GEMM2
  const float il0 = 1.f / lsum[0];
  const float il1 = 1.f / lsum[1];
#pragma unroll
  for (int mo = 0; mo < 2; ++mo) {
    const float myil = (mo == 0) ? il0 : il1;
#pragma unroll
    for (int i = 0; i < 4; ++i) {
      const float wv = __shfl(myil, lk * 4 + i);
      const int srow = f * CTPF + qb + mo * 16 + lk * 4 + i;
      const size_t obase = (size_t)(b * CS + srow) * CDM + h * CHD;
#pragma unroll
      for (int no = 0; no < 4; ++no) {
        const float val = accO[mo][no][i] * wv;
        const ushort hh = f32_bf16_rne(val);
        Oh[obase + no * 16 + l15] = hh;
        Ol[obase + no * 16 + l15] = f32_bf16_rne(val - bf16_f32(hh));
      }
    }
  }
}

// ---------------------------------------------------------------------------
extern "C" void kernel_launch(void* const* d_in, const int* in_sizes, int n_in,
                              void* d_out, int out_size, void* d_ws, size_t ws_size,
                              hipStream_t stream) {
  const float* x       = (const float*)d_in[0];
  const float* Wqkv    = (const float*)d_in[1];
  const float* bqkv    = (const float*)d_in[2];
  const float* q_scale = (const float*)d_in[3];
  const float* k_scale = (const float*)d_in[4];
  const float* Wout    = (const float*)d_in[5];
  const float* bout    = (const float*)d_in[6];
  float* out = (float*)d_out;

  // Workspace layout (ushort units). Temporal aliasing:
  //  region0 (50.3 MB): qkv fp32 [live GEMM1..prep]  ->  Oh/Ol [live attn..GEMM2]
  //  region1 (50.3 MB): xh/xl/Wqh/Wql [live split..GEMM1] -> Qh..Vtl [prep..attn]
  //  region2 ( 4.2 MB): Wouth/Woutl [live split..GEMM2]
  ushort* W = (ushort*)d_ws;
  const size_t qkvN = (size_t)(CB * CS) * (3 * CDM);   // 12.58M floats
  const size_t perA = (size_t)CB * CH * CS * CHD;      // 4.19M elems
  const size_t WqN  = (size_t)(3 * CDM) * CDM;         // 3.15M
  const size_t WoN  = (size_t)CDM * CDM;               // 1.05M

  float*  qkvF = (float*)W;
  ushort* Oh   = W;                    // aliases qkvF (dead after prep)
  ushort* Ol   = W + perA;
  ushort* R1   = W + 2 * qkvN;
  ushort* Qh = R1;            ushort* Ql = R1 + perA;
  ushort* Kh = R1 + 2 * perA; ushort* Kl = R1 + 3 * perA;
  ushort* Vth = R1 + 4 * perA; ushort* Vtl = R1 + 5 * perA;
  ushort* xh  = R1;            ushort* xl  = R1 + perA;   // alias Qh/Ql
  ushort* Wqh = R1 + 2 * perA; ushort* Wql = Wqh + WqN;   // alias Kh..
  ushort* Wouth = R1 + 6 * perA; ushort* Woutl = Wouth + WoN;

  // 0) one-time fp32 -> bf16 h/l splits (memory-bound)
  split_pass<<<2048, 256, 0, stream>>>(x, xh, xl, (int)(perA / 8));
  split_pass<<<1536, 256, 0, stream>>>(Wqkv, Wqh, Wql, (int)(WqN / 8));
  split_pass<<<512, 256, 0, stream>>>(Wout, Wouth, Woutl, (int)(WoN / 8));

  // 1) qkv = x @ Wqkv^T + bqkv
  dim3 g1((3 * CDM) / 128, (CB * CS) / 128);
  gemm_ps<<<g1, 256, 0, stream>>>(xh, xl, Wqh, Wql, bqkv, qkvF,
                                  CB * CS, 3 * CDM, CDM);

  // 2) RMSNorm + RoPE; pre-split Q (scaled), K, Vt to bf16 h/l
  dim3 g2(CS / 64, CH, CB);
  qkv_prep<<<g2, 256, 0, stream>>>(qkvF, q_scale, k_scale,
                                   Qh, Ql, Kh, Kl, Vth, Vtl);

  // 3) frame-block-causal attention on MFMA -> pre-split O
  //    grid (batch, head, fsel): balanced complementary frame pairs per CU
  dim3 g3(CB, CH, CNF);
  attn_fwd_mfma<<<g3, 256, 0, stream>>>(Qh, Ql, Kh, Kl, Vth, Vtl, Oh, Ol);

  // 4) out = O @ Wout^T + bout
  dim3 g4(CDM / 128, (CB * CS) / 128);
  gemm_ps<<<g4, 256, 0, stream>>>(Oh, Ol, Wouth, Woutl, bout, out,
                                  CB * CS, CDM, CDM);
}